// Round 11
// baseline (77.336 us; speedup 1.0000x reference)
//
#include <hip/hip_runtime.h>

#define NBATCH 8
#define S 2048
#define D 128
#define BQ 32
#define BK 64
#define NKT 32
#define NQT 64
#define INV_SQRT_D 0.08838834764831845f

typedef __bf16 bfv8 __attribute__((ext_vector_type(8)));
typedef float f32x4 __attribute__((ext_vector_type(4)));

__device__ __forceinline__ f32x4 mfma16(bfv8 a, bfv8 b, f32x4 c) {
    return __builtin_amdgcn_mfma_f32_16x16x32_bf16(a, b, c, 0, 0, 0);
}

__device__ __forceinline__ unsigned int pack2(float lo, float hi) {
    unsigned short a = __builtin_bit_cast(unsigned short, (__bf16)lo);
    unsigned short b = __builtin_bit_cast(unsigned short, (__bf16)hi);
    return (unsigned int)a | ((unsigned int)b << 16);
}

// ============ prep: K -> bf16 swizzled tiles; V -> bf16 transposed swizzled ============
// kb tile (b,kt): 64 rows x 16 units(16B); unit stored at u^(row&7)
// vtb tile (b,kt): 128 d-rows x 8 units(16B); unit stored at u^(d&7)
__global__ __launch_bounds__(256) void prep_kernel(
    const float* __restrict__ k, const float* __restrict__ v,
    __bf16* __restrict__ kb, __bf16* __restrict__ vtb)
{
    __shared__ __bf16 lds[64][132];
    const int bidx = blockIdx.x;
    const int tid  = threadIdx.x;

    if (bidx < 1024) {                 // K part: fully coalesced
        const int t   = bidx * 256 + tid;
        const int b   = t >> 15;
        const int kt  = (t >> 10) & 31;
        const int row = (t >> 4) & 63;
        const int u   = t & 15;
        const float4 f0 = *(const float4*)&k[((size_t)(b * S + kt * 64 + row)) * D + u * 8];
        const float4 f1 = *(const float4*)&k[((size_t)(b * S + kt * 64 + row)) * D + u * 8 + 4];
        bfv8 o;
        o[0] = (__bf16)f0.x; o[1] = (__bf16)f0.y; o[2] = (__bf16)f0.z; o[3] = (__bf16)f0.w;
        o[4] = (__bf16)f1.x; o[5] = (__bf16)f1.y; o[6] = (__bf16)f1.z; o[7] = (__bf16)f1.w;
        const size_t unit = ((size_t)((b * 32 + kt) * 64 + row)) * 16 + (u ^ (row & 7));
        *(bfv8*)&kb[unit * 8] = o;
    } else {                           // V part: LDS-staged transpose
        const int vb = bidx - 1024;
        const int b  = vb >> 5;
        const int kt = vb & 31;
#pragma unroll
        for (int p = 0; p < 8; ++p) {
            const int idx = p * 256 + tid;
            const int kv  = idx >> 5;
            const int c4  = idx & 31;
            const float4 f = *(const float4*)&v[((size_t)(b * S + kt * 64 + kv)) * D + c4 * 4];
            __bf16* dst = &lds[kv][c4 * 4];
            dst[0] = (__bf16)f.x; dst[1] = (__bf16)f.y; dst[2] = (__bf16)f.z; dst[3] = (__bf16)f.w;
        }
        __syncthreads();
#pragma unroll
        for (int p = 0; p < 4; ++p) {
            const int idx = p * 256 + tid;
            const int d   = idx >> 3;
            const int u   = idx & 7;
            bfv8 o;
#pragma unroll
            for (int j = 0; j < 8; ++j) o[j] = lds[u * 8 + j][d];
            const size_t unit = ((size_t)((b * 32 + kt) * 128 + d)) * 8 + (u ^ (d & 7));
            *(bfv8*)&vtb[unit * 8] = o;
        }
    }
}

// ============ main: two-pass, all K/V frags direct from global pre-swizzled bufs ============
__global__ __launch_bounds__(256) void attn_direct(
    const float* __restrict__ q, const float* __restrict__ rep,
    const __bf16* __restrict__ kb, const __bf16* __restrict__ vtb,
    float* __restrict__ out, float* __restrict__ attn)
{
    __shared__ __attribute__((aligned(16))) __bf16 qs[BQ][136];
    __shared__ __attribute__((aligned(16))) __bf16 ps[2][BQ][72];   // P double-buffer
    __shared__ float redsum[2][2][16];
    __shared__ float dinv_lds[BQ];

    const int tid = threadIdx.x;
    const int bid = blockIdx.x;
    const int b   = bid & 7;
    const int g   = bid >> 3;
    // balanced pairing (r8 proven, -5.5us): CU gets qt pair (63-g, g)
    const int qt  = (g < 32) ? (63 - g) : (g - 32);
    const int i0  = qt * BQ;
    const int NT  = ((qt * BQ + (BQ - 2)) >> 6) + 1;

    const int lane = tid & 63;
    const int w  = tid >> 6;
    const int rg = w >> 1;
    const int ch = w & 1;
    const int lr = lane & 15;
    const int lg = lane >> 4;

    // ---- stage Q -> bf16 LDS ----
    for (int c = tid; c < BQ * 16; c += 256) {
        const int row = c >> 4, c8 = c & 15;
        const float4 f0 = *(const float4*)&q[((size_t)(b * S + i0 + row)) * D + c8 * 8];
        const float4 f1 = *(const float4*)&q[((size_t)(b * S + i0 + row)) * D + c8 * 8 + 4];
        bfv8 t;
        t[0] = (__bf16)f0.x; t[1] = (__bf16)f0.y; t[2] = (__bf16)f0.z; t[3] = (__bf16)f0.w;
        t[4] = (__bf16)f1.x; t[5] = (__bf16)f1.y; t[6] = (__bf16)f1.z; t[7] = (__bf16)f1.w;
        *(bfv8*)&qs[row][c8 * 8] = t;
    }

    // per-lane column-validity bitmasks
    unsigned int vm0 = 0, vm1 = 0;
    for (int kt = 0; kt < NT; ++kt) {
        const unsigned int t0 = (rep[(size_t)b * S + kt * BK + ch * 32 + lr]      > 0.5f) ? 1u : 0u;
        const unsigned int t1 = (rep[(size_t)b * S + kt * BK + ch * 32 + 16 + lr] > 0.5f) ? 1u : 0u;
        vm0 |= t0 << kt;
        vm1 |= t1 << kt;
    }

    int  i_r[4];
    bool bi[4];
#pragma unroll
    for (int r = 0; r < 4; ++r) {
        i_r[r] = i0 + rg * 16 + lg * 4 + r;
        bi[r]  = rep[(size_t)b * S + i_r[r]] > 0.5f;
    }
    __syncthreads();   // qs ready

    bfv8 qa[4];
#pragma unroll
    for (int ks = 0; ks < 4; ++ks)
        qa[ks] = *(const bfv8*)&qs[rg * 16 + lr][ks * 32 + lg * 8];

    // ---- K fragment global offsets (r7-verified) ----
    const int krow = ch * 32 + lr;
    const int csw  = krow & 7;
    int koff[4];
#pragma unroll
    for (int ks = 0; ks < 4; ++ks)
        koff[ks] = krow * 256 + (((ks * 4 + lg) ^ csw) << 4);
    const char* kbb = (const char*)kb + (((size_t)(b * 32)) << 14);

    // ---- V fragment global offsets (r10-verified) ----
    const int csv = lr & 7;
    int voff[2][4];
#pragma unroll
    for (int ks = 0; ks < 2; ++ks)
#pragma unroll
        for (int nf = 0; nf < 4; ++nf)
            voff[ks][nf] = (ch * 64 + nf * 16 + lr) * 128 + (((ks * 4 + lg) ^ csv) << 4);
    const char* vbb = (const char*)vtb + (((size_t)(b * 32)) << 14);

    // ============ pass A: barrier-free masked row sums (r7/r8 proven) ============
    float lsum[4] = {0.f, 0.f, 0.f, 0.f};
#pragma unroll 2
    for (int kt = 0; kt < NT; ++kt) {
        const char* tp = kbb + ((size_t)kt << 14);
        bfv8 kf0[4], kf1[4];
#pragma unroll
        for (int ks = 0; ks < 4; ++ks) {
            kf0[ks] = *(const bfv8*)(tp + koff[ks]);
            kf1[ks] = *(const bfv8*)(tp + koff[ks] + 4096);
        }
        f32x4 acc0 = {0.f, 0.f, 0.f, 0.f}, acc1 = {0.f, 0.f, 0.f, 0.f};
#pragma unroll
        for (int ks = 0; ks < 4; ++ks) {
            acc0 = mfma16(qa[ks], kf0[ks], acc0);
            acc1 = mfma16(qa[ks], kf1[ks], acc1);
        }

        const int j0 = kt * BK + ch * 32 + lr;
        const int j1 = j0 + 16;
        const bool vj0 = (vm0 >> kt) & 1;
        const bool vj1 = (vm1 >> kt) & 1;
#pragma unroll
        for (int r = 0; r < 4; ++r) {
            const int i = i_r[r];
            const float p0 = (bi[r] && vj0 && (j0 < i))
                ? __expf(acc0[r] * INV_SQRT_D - (float)(i - j0)) : 0.f;
            const float p1 = (bi[r] && vj1 && (j1 < i))
                ? __expf(acc1[r] * INV_SQRT_D - (float)(i - j1)) : 0.f;
            lsum[r] += p0 + p1;
        }
    }

    // ---- reduce row sums ----
#pragma unroll
    for (int r = 0; r < 4; ++r) {
        lsum[r] += __shfl_xor(lsum[r], 1);
        lsum[r] += __shfl_xor(lsum[r], 2);
        lsum[r] += __shfl_xor(lsum[r], 4);
        lsum[r] += __shfl_xor(lsum[r], 8);
    }
    if (lr == 0) {
#pragma unroll
        for (int r = 0; r < 4; ++r) redsum[rg][ch][lg * 4 + r] = lsum[r];
    }

    // prefetch pass-B K(0) fragments into registers (in flight across the reduce barriers)
    bfv8 kc0[4], kc1[4];
#pragma unroll
    for (int ks = 0; ks < 4; ++ks) {
        kc0[ks] = *(const bfv8*)(kbb + koff[ks]);
        kc1[ks] = *(const bfv8*)(kbb + koff[ks] + 4096);
    }

    __syncthreads();
    if (tid < BQ) {
        const float s = redsum[tid >> 4][0][tid & 15] + redsum[tid >> 4][1][tid & 15];
        dinv_lds[tid] = 1.f / (s + ((s == 0.f) ? 1.f : 0.f) + 1e-20f);
    }
    __syncthreads();

    float dinv[4];
#pragma unroll
    for (int r = 0; r < 4; ++r) dinv[r] = dinv_lds[rg * 16 + lg * 4 + r];

    // ============ pass B: 1 barrier/iter, zero staging, reg-double-buffered K ============
    f32x4 oacc[4];
#pragma unroll
    for (int nf = 0; nf < 4; ++nf) oacc[nf] = (f32x4){0.f, 0.f, 0.f, 0.f};

    const int arow = tid >> 3;
    const int ac   = (tid & 7) * 8;

    for (int kt = 0; kt < NT; ++kt) {
        const int pp = kt & 1;

        // QK(kt) from registers (loaded previous iter / prologue)
        f32x4 acc0 = {0.f, 0.f, 0.f, 0.f}, acc1 = {0.f, 0.f, 0.f, 0.f};
#pragma unroll
        for (int ks = 0; ks < 4; ++ks) {
            acc0 = mfma16(qa[ks], kc0[ks], acc0);
            acc1 = mfma16(qa[ks], kc1[ks], acc1);
        }

        const int j0 = kt * BK + ch * 32 + lr;
        const int j1 = j0 + 16;
        const bool vj0 = (vm0 >> kt) & 1;
        const bool vj1 = (vm1 >> kt) & 1;
#pragma unroll
        for (int r = 0; r < 4; ++r) {
            const int i = i_r[r];
            const float p0 = (bi[r] && vj0 && (j0 < i))
                ? __expf(acc0[r] * INV_SQRT_D - (float)(i - j0)) * dinv[r] : 0.f;
            const float p1 = (bi[r] && vj1 && (j1 < i))
                ? __expf(acc1[r] * INV_SQRT_D - (float)(i - j1)) * dinv[r] : 0.f;
            ps[pp][rg * 16 + lg * 4 + r][ch * 32 + lr]      = (__bf16)p0;
            ps[pp][rg * 16 + lg * 4 + r][ch * 32 + 16 + lr] = (__bf16)p1;
        }

        // single barrier: publish ps[pp] (ps[2] double-buffer fences kt+2 writes transitively)
        asm volatile("s_waitcnt lgkmcnt(0)" ::: "memory");
        __builtin_amdgcn_s_barrier();
        asm volatile("" ::: "memory");

        // prefetch K(kt+1) fragments (oldest loads in queue -> never wait on stores)
        if (kt + 1 < NT) {
            const char* tp = kbb + ((size_t)(kt + 1) << 14);
#pragma unroll
            for (int ks = 0; ks < 4; ++ks) {
                kc0[ks] = *(const bfv8*)(tp + koff[ks]);
                kc1[ks] = *(const bfv8*)(tp + koff[ks] + 4096);
            }
        }

        // PV(kt): V fragments direct from global (r10-verified), P from LDS
        const char* vtp = vbb + ((size_t)kt << 14);
#pragma unroll
        for (int ks = 0; ks < 2; ++ks) {
            const bfv8 pa = *(const bfv8*)&ps[pp][rg * 16 + lr][ks * 32 + lg * 8];
#pragma unroll
            for (int nf = 0; nf < 4; ++nf) {
                const bfv8 vf = *(const bfv8*)(vtp + voff[ks][nf]);
                oacc[nf] = mfma16(pa, vf, oacc[nf]);
            }
        }

        // coalesced attn tile store from ps (issued last; fire-and-forget)
        {
            const bfv8 t = *(const bfv8*)&ps[pp][arow][ac];
            float4 f0, f1;
            f0.x = (float)t[0]; f0.y = (float)t[1]; f0.z = (float)t[2]; f0.w = (float)t[3];
            f1.x = (float)t[4]; f1.y = (float)t[5]; f1.z = (float)t[6]; f1.w = (float)t[7];
            float* ap = &attn[((size_t)(b * S + i0 + arow)) * S + kt * BK + ac];
            *(float4*)ap = f0;
            *(float4*)(ap + 4) = f1;
        }
    }

    // ---- write out ----
#pragma unroll
    for (int nf = 0; nf < 4; ++nf)
#pragma unroll
        for (int r = 0; r < 4; ++r)
            out[((size_t)(b * S + i_r[r])) * D + ch * 64 + nf * 16 + lr] = oacc[nf][r];

    // ---- zero-fill attn tiles above the block diagonal ----
    const int zt = NKT - NT;
    const float4 z4 = make_float4(0.f, 0.f, 0.f, 0.f);
    for (int u = tid; u < zt * 512; u += 256) {
        const int t   = u >> 9;
        const int rem = u & 511;
        const int row = rem >> 4;
        const int c4  = rem & 15;
        *(float4*)&attn[((size_t)(b * S + i0 + row)) * S + (NT + t) * BK + c4 * 4] = z4;
    }
}

// ============ fallback (proven) if ws too small ============
__global__ __launch_bounds__(256) void attn_kernel_fb(
    const float* __restrict__ q, const float* __restrict__ k,
    const float* __restrict__ v, const float* __restrict__ rep,
    float* __restrict__ out, float* __restrict__ attn)
{
    __shared__ __attribute__((aligned(16))) __bf16 qs [BQ][136];
    __shared__ __attribute__((aligned(16))) __bf16 ksm[BK][136];
    __shared__ __attribute__((aligned(16))) __bf16 vsT[D][72];
    __shared__ __attribute__((aligned(16))) __bf16 psl[BQ][72];
    __shared__ float redsum[2][2][16];
    __shared__ float dinv_lds[BQ];

    const int tid  = threadIdx.x;
    const int bid  = blockIdx.x;
    const int b    = bid & 7;
    const int qt   = (NQT - 1) - (bid >> 3);
    const int i0   = qt * BQ;
    const int NT   = ((qt * BQ + (BQ - 2)) >> 6) + 1;

    const int lane = tid & 63;
    const int w    = tid >> 6;
    const int rg   = w >> 1;
    const int ch   = w & 1;
    const int lr   = lane & 15;
    const int lg   = lane >> 4;

    for (int c = tid; c < BQ * 16; c += 256) {
        const int row = c >> 4, c8 = c & 15;
        const float4 f0 = *(const float4*)&q[((size_t)(b * S + i0 + row)) * D + c8 * 8];
        const float4 f1 = *(const float4*)&q[((size_t)(b * S + i0 + row)) * D + c8 * 8 + 4];
        bfv8 t;
        t[0] = (__bf16)f0.x; t[1] = (__bf16)f0.y; t[2] = (__bf16)f0.z; t[3] = (__bf16)f0.w;
        t[4] = (__bf16)f1.x; t[5] = (__bf16)f1.y; t[6] = (__bf16)f1.z; t[7] = (__bf16)f1.w;
        *(bfv8*)&qs[row][c8 * 8] = t;
    }
    __syncthreads();

    bfv8 qa[4];
#pragma unroll
    for (int ks = 0; ks < 4; ++ks)
        qa[ks] = *(const bfv8*)&qs[rg * 16 + lr][ks * 32 + lg * 8];

    int  i_r[4];
    bool bi[4];
#pragma unroll
    for (int r = 0; r < 4; ++r) {
        i_r[r] = i0 + rg * 16 + lg * 4 + r;
        bi[r]  = rep[(size_t)b * S + i_r[r]] > 0.5f;
    }

    float lsum[4] = {0.f, 0.f, 0.f, 0.f};
    for (int kt = 0; kt < NT; ++kt) {
        __syncthreads();
        for (int c = tid; c < BK * 16; c += 256) {
            const int row = c >> 4, c8 = c & 15;
            const float4 f0 = *(const float4*)&k[((size_t)(b * S + kt * BK + row)) * D + c8 * 8];
            const float4 f1 = *(const float4*)&k[((size_t)(b * S + kt * BK + row)) * D + c8 * 8 + 4];
            bfv8 t;
            t[0] = (__bf16)f0.x; t[1] = (__bf16)f0.y; t[2] = (__bf16)f0.z; t[3] = (__bf16)f0.w;
            t[4] = (__bf16)f1.x; t[5] = (__bf16)f1.y; t[6] = (__bf16)f1.z; t[7] = (__bf16)f1.w;
            *(bfv8*)&ksm[row][c8 * 8] = t;
        }
        __syncthreads();

        f32x4 acc0 = {0.f, 0.f, 0.f, 0.f}, acc1 = {0.f, 0.f, 0.f, 0.f};
#pragma unroll
        for (int ks = 0; ks < 4; ++ks) {
            const bfv8 b0 = *(const bfv8*)&ksm[ch * 32 + lr][ks * 32 + lg * 8];
            const bfv8 b1 = *(const bfv8*)&ksm[ch * 32 + 16 + lr][ks * 32 + lg * 8];
            acc0 = mfma16(qa[ks], b0, acc0);
            acc1 = mfma16(qa[ks], b1, acc1);
        }
        const int j0 = kt * BK + ch * 32 + lr;
        const int j1 = j0 + 16;
        const bool vj0 = rep[(size_t)b * S + j0] > 0.5f;
        const bool vj1 = rep[(size_t)b * S + j1] > 0.5f;
#pragma unroll
        for (int r = 0; r < 4; ++r) {
            const int i = i_r[r];
            const float p0 = (bi[r] && vj0 && (j0 < i))
                ? __expf(acc0[r] * INV_SQRT_D - (float)(i - j0)) : 0.f;
            const float p1 = (bi[r] && vj1 && (j1 < i))
                ? __expf(acc1[r] * INV_SQRT_D - (float)(i - j1)) : 0.f;
            lsum[r] += p0 + p1;
        }
    }

#pragma unroll
    for (int r = 0; r < 4; ++r) {
        lsum[r] += __shfl_xor(lsum[r], 1);
        lsum[r] += __shfl_xor(lsum[r], 2);
        lsum[r] += __shfl_xor(lsum[r], 4);
        lsum[r] += __shfl_xor(lsum[r], 8);
    }
    if (lr == 0) {
#pragma unroll
        for (int r = 0; r < 4; ++r) redsum[rg][ch][lg * 4 + r] = lsum[r];
    }
    __syncthreads();
    if (tid < BQ) {
        const float s = redsum[tid >> 4][0][tid & 15] + redsum[tid >> 4][1][tid & 15];
        dinv_lds[tid] = 1.f / (s + ((s == 0.f) ? 1.f : 0.f) + 1e-20f);
    }
    __syncthreads();

    float dinv[4];
#pragma unroll
    for (int r = 0; r < 4; ++r) dinv[r] = dinv_lds[rg * 16 + lg * 4 + r];

    f32x4 oacc[4];
#pragma unroll
    for (int nf = 0; nf < 4; ++nf) oacc[nf] = (f32x4){0.f, 0.f, 0.f, 0.f};

    for (int kt = 0; kt < NT; ++kt) {
        __syncthreads();
        for (int c = tid; c < BK * 16; c += 256) {
            const int row = c >> 4, c8 = c & 15;
            const float4 f0 = *(const float4*)&k[((size_t)(b * S + kt * BK + row)) * D + c8 * 8];
            const float4 f1 = *(const float4*)&k[((size_t)(b * S + kt * BK + row)) * D + c8 * 8 + 4];
            bfv8 t;
            t[0] = (__bf16)f0.x; t[1] = (__bf16)f0.y; t[2] = (__bf16)f0.z; t[3] = (__bf16)f0.w;
            t[4] = (__bf16)f1.x; t[5] = (__bf16)f1.y; t[6] = (__bf16)f1.z; t[7] = (__bf16)f1.w;
            *(bfv8*)&ksm[row][c8 * 8] = t;
        }
        for (int u = tid; u < 1024; u += 256) {
            const int p  = u & 31;
            const int dq = u >> 5;
            const float4 va = *(const float4*)&v[((size_t)(b * S + kt * BK + 2 * p)) * D + dq * 4];
            const float4 vb = *(const float4*)&v[((size_t)(b * S + kt * BK + 2 * p + 1)) * D + dq * 4];
            *(unsigned int*)&vsT[dq * 4 + 0][2 * p] = pack2(va.x, vb.x);
            *(unsigned int*)&vsT[dq * 4 + 1][2 * p] = pack2(va.y, vb.y);
            *(unsigned int*)&vsT[dq * 4 + 2][2 * p] = pack2(va.z, vb.z);
            *(unsigned int*)&vsT[dq * 4 + 3][2 * p] = pack2(va.w, vb.w);
        }
        __syncthreads();

        f32x4 acc0 = {0.f, 0.f, 0.f, 0.f}, acc1 = {0.f, 0.f, 0.f, 0.f};
#pragma unroll
        for (int ks = 0; ks < 4; ++ks) {
            const bfv8 b0 = *(const bfv8*)&ksm[ch * 32 + lr][ks * 32 + lg * 8];
            const bfv8 b1 = *(const bfv8*)&ksm[ch * 32 + 16 + lr][ks * 32 + lg * 8];
            acc0 = mfma16(qa[ks], b0, acc0);
            acc1 = mfma16(qa[ks], b1, acc1);
        }
        const int j0 = kt * BK + ch * 32 + lr;
        const int j1 = j0 + 16;
        const bool vj0 = rep[(size_t)b * S + j0] > 0.5f;
        const bool vj1 = rep[(size_t)b * S + j1] > 0.5f;
#pragma unroll
        for (int r = 0; r < 4; ++r) {
            const int i = i_r[r];
            const float p0 = (bi[r] && vj0 && (j0 < i))
                ? __expf(acc0[r] * INV_SQRT_D - (float)(i - j0)) * dinv[r] : 0.f;
            const float p1 = (bi[r] && vj1 && (j1 < i))
                ? __expf(acc1[r] * INV_SQRT_D - (float)(i - j1)) * dinv[r] : 0.f;
            attn[((size_t)(b * S + i)) * S + j0] = p0;
            attn[((size_t)(b * S + i)) * S + j1] = p1;
            psl[rg * 16 + lg * 4 + r][ch * 32 + lr]      = (__bf16)p0;
            psl[rg * 16 + lg * 4 + r][ch * 32 + 16 + lr] = (__bf16)p1;
        }
        __syncthreads();

#pragma unroll
        for (int ks = 0; ks < 2; ++ks) {
            const bfv8 pa = *(const bfv8*)&psl[rg * 16 + lr][ks * 32 + lg * 8];
#pragma unroll
            for (int nf = 0; nf < 4; ++nf) {
                const bfv8 vf = *(const bfv8*)&vsT[ch * 64 + nf * 16 + lr][ks * 32 + lg * 8];
                oacc[nf] = mfma16(pa, vf, oacc[nf]);
            }
        }
    }

#pragma unroll
    for (int nf = 0; nf < 4; ++nf)
#pragma unroll
        for (int r = 0; r < 4; ++r)
            out[((size_t)(b * S + i_r[r])) * D + ch * 64 + nf * 16 + lr] = oacc[nf][r];

    const int zt = NKT - NT;
    const float4 z4 = make_float4(0.f, 0.f, 0.f, 0.f);
    for (int u = tid; u < zt * 512; u += 256) {
        const int t   = u >> 9;
        const int rem = u & 511;
        const int row = rem >> 4;
        const int c4  = rem & 15;
        *(float4*)&attn[((size_t)(b * S + i0 + row)) * S + (NT + t) * BK + c4 * 4] = z4;
    }
}

extern "C" void kernel_launch(void* const* d_in, const int* in_sizes, int n_in,
                              void* d_out, int out_size, void* d_ws, size_t ws_size,
                              hipStream_t stream)
{
    const float* q   = (const float*)d_in[0];
    const float* k   = (const float*)d_in[1];
    const float* v   = (const float*)d_in[2];
    const float* rep = (const float*)d_in[3];
    float* out  = (float*)d_out;
    float* attn = out + (size_t)NBATCH * S * D;

    const size_t kb_elems = (size_t)NBATCH * S * D;   // bf16 elems (4MB each buf)
    const size_t need     = kb_elems * 2 * 2;         // kb + vtb bytes = 16.78 MB

    if (ws_size < need) {
        hipLaunchKernelGGL(attn_kernel_fb, dim3(NBATCH * NQT), dim3(256), 0, stream,
                           q, k, v, rep, out, attn);
        return;
    }

    __bf16* kb  = (__bf16*)d_ws;
    __bf16* vtb = kb + kb_elems;

    hipLaunchKernelGGL(prep_kernel, dim3(1280), dim3(256), 0, stream, k, v, kb, vtb);
    hipLaunchKernelGGL(attn_direct, dim3(NBATCH * NQT), dim3(256), 0, stream,
                       q, rep, kb, vtb, out, attn);
}

// Round 12
// 71.906 us; speedup vs baseline: 1.0755x; 1.0755x over previous
//
#include <hip/hip_runtime.h>

#define NBATCH 8
#define S 2048
#define D 128
#define BQ 32
#define BK 64
#define NKT 32
#define NQT 64
#define INV_SQRT_D 0.08838834764831845f

typedef __bf16 bfv8 __attribute__((ext_vector_type(8)));
typedef float f32x4 __attribute__((ext_vector_type(4)));

__device__ __forceinline__ f32x4 mfma16(bfv8 a, bfv8 b, f32x4 c) {
    return __builtin_amdgcn_mfma_f32_16x16x32_bf16(a, b, c, 0, 0, 0);
}

__device__ __forceinline__ unsigned int pack2(float lo, float hi) {
    unsigned short a = __builtin_bit_cast(unsigned short, (__bf16)lo);
    unsigned short b = __builtin_bit_cast(unsigned short, (__bf16)hi);
    return (unsigned int)a | ((unsigned int)b << 16);
}

__device__ __forceinline__ void gload_lds16(const void* g, void* l) {
    __builtin_amdgcn_global_load_lds(
        (const __attribute__((address_space(1))) unsigned int*)g,
        (__attribute__((address_space(3))) unsigned int*)l, 16, 0, 0);
}

// ============ prep: K -> bf16 swizzled tiles; V -> bf16 transposed swizzled ============
// kb tile (b,kt): 64 rows x 16 units(16B); unit stored at u^(row&7)
// vtb tile (b,kt): 128 d-rows x 8 units(16B); unit stored at u^(d&7)
__global__ __launch_bounds__(256) void prep_kernel(
    const float* __restrict__ k, const float* __restrict__ v,
    __bf16* __restrict__ kb, __bf16* __restrict__ vtb)
{
    __shared__ __bf16 lds[64][132];
    const int bidx = blockIdx.x;
    const int tid  = threadIdx.x;

    if (bidx < 1024) {                 // K part: fully coalesced
        const int t   = bidx * 256 + tid;
        const int b   = t >> 15;
        const int kt  = (t >> 10) & 31;
        const int row = (t >> 4) & 63;
        const int u   = t & 15;
        const float4 f0 = *(const float4*)&k[((size_t)(b * S + kt * 64 + row)) * D + u * 8];
        const float4 f1 = *(const float4*)&k[((size_t)(b * S + kt * 64 + row)) * D + u * 8 + 4];
        bfv8 o;
        o[0] = (__bf16)f0.x; o[1] = (__bf16)f0.y; o[2] = (__bf16)f0.z; o[3] = (__bf16)f0.w;
        o[4] = (__bf16)f1.x; o[5] = (__bf16)f1.y; o[6] = (__bf16)f1.z; o[7] = (__bf16)f1.w;
        const size_t unit = ((size_t)((b * 32 + kt) * 64 + row)) * 16 + (u ^ (row & 7));
        *(bfv8*)&kb[unit * 8] = o;
    } else {                           // V part: LDS-staged transpose
        const int vb = bidx - 1024;
        const int b  = vb >> 5;
        const int kt = vb & 31;
#pragma unroll
        for (int p = 0; p < 8; ++p) {
            const int idx = p * 256 + tid;
            const int kv  = idx >> 5;
            const int c4  = idx & 31;
            const float4 f = *(const float4*)&v[((size_t)(b * S + kt * 64 + kv)) * D + c4 * 4];
            __bf16* dst = &lds[kv][c4 * 4];
            dst[0] = (__bf16)f.x; dst[1] = (__bf16)f.y; dst[2] = (__bf16)f.z; dst[3] = (__bf16)f.w;
        }
        __syncthreads();
#pragma unroll
        for (int p = 0; p < 4; ++p) {
            const int idx = p * 256 + tid;
            const int d   = idx >> 3;
            const int u   = idx & 7;
            bfv8 o;
#pragma unroll
            for (int j = 0; j < 8; ++j) o[j] = lds[u * 8 + j][d];
            const size_t unit = ((size_t)((b * 32 + kt) * 128 + d)) * 8 + (u ^ (d & 7));
            *(bfv8*)&vtb[unit * 8] = o;
        }
    }
}

// ============ main: hybrid — K frags direct-from-global prefetched in regs,
//                              V staged via gload_lds double-buffer (r8-proven) ============
__global__ __launch_bounds__(256) void attn_hybrid(
    const float* __restrict__ q, const float* __restrict__ rep,
    const __bf16* __restrict__ kb, const __bf16* __restrict__ vtb,
    float* __restrict__ out, float* __restrict__ attn)
{
    __shared__ __attribute__((aligned(16))) __bf16 vslot[2][8192];  // V tiles, 16KB each
    __shared__ __attribute__((aligned(16))) __bf16 qs[BQ][136];
    __shared__ __attribute__((aligned(16))) __bf16 ps[BQ][72];
    __shared__ float redsum[2][2][16];
    __shared__ float dinv_lds[BQ];

    const int tid = threadIdx.x;
    const int bid = blockIdx.x;
    const int b   = bid & 7;
    const int g   = bid >> 3;
    // balanced pairing (r8 proven, -5.5us): CU gets qt pair (63-g, g)
    const int qt  = (g < 32) ? (63 - g) : (g - 32);
    const int i0  = qt * BQ;
    const int NT  = ((qt * BQ + (BQ - 2)) >> 6) + 1;

    const int lane = tid & 63;
    const int w  = tid >> 6;
    const int rg = w >> 1;
    const int ch = w & 1;
    const int lr = lane & 15;
    const int lg = lane >> 4;

    auto stageV = [&](int kt, int slot) {
        const char* src = (const char*)vtb + (((size_t)(b * 32 + kt)) << 14);
        char* dst = (char*)&vslot[slot][0];
#pragma unroll
        for (int i2 = 0; i2 < 4; ++i2) {
            const int n0 = (w * 4 + i2) * 64;
            gload_lds16(src + (size_t)(n0 + lane) * 16, dst + (size_t)n0 * 16);
        }
    };
    auto vfrag = [&](int slot, int drow, int u) -> bfv8 {
        return *(const bfv8*)&vslot[slot][(drow * 8 + (u ^ (drow & 7))) * 8];
    };

    // ---- prologue: issue V(0) prefetch now (lands during pass A) ----
    stageV(0, 0);

    // stage Q -> bf16 LDS
    for (int c = tid; c < BQ * 16; c += 256) {
        const int row = c >> 4, c8 = c & 15;
        const float4 f0 = *(const float4*)&q[((size_t)(b * S + i0 + row)) * D + c8 * 8];
        const float4 f1 = *(const float4*)&q[((size_t)(b * S + i0 + row)) * D + c8 * 8 + 4];
        bfv8 t;
        t[0] = (__bf16)f0.x; t[1] = (__bf16)f0.y; t[2] = (__bf16)f0.z; t[3] = (__bf16)f0.w;
        t[4] = (__bf16)f1.x; t[5] = (__bf16)f1.y; t[6] = (__bf16)f1.z; t[7] = (__bf16)f1.w;
        *(bfv8*)&qs[row][c8 * 8] = t;
    }

    // per-lane column-validity bitmasks
    unsigned int vm0 = 0, vm1 = 0;
    for (int kt = 0; kt < NT; ++kt) {
        const unsigned int t0 = (rep[(size_t)b * S + kt * BK + ch * 32 + lr]      > 0.5f) ? 1u : 0u;
        const unsigned int t1 = (rep[(size_t)b * S + kt * BK + ch * 32 + 16 + lr] > 0.5f) ? 1u : 0u;
        vm0 |= t0 << kt;
        vm1 |= t1 << kt;
    }

    int  i_r[4];
    bool bi[4];
#pragma unroll
    for (int r = 0; r < 4; ++r) {
        i_r[r] = i0 + rg * 16 + lg * 4 + r;
        bi[r]  = rep[(size_t)b * S + i_r[r]] > 0.5f;
    }
    __syncthreads();   // qs ready; V(0) drained into vslot[0]

    bfv8 qa[4];
#pragma unroll
    for (int ks = 0; ks < 4; ++ks)
        qa[ks] = *(const bfv8*)&qs[rg * 16 + lr][ks * 32 + lg * 8];

    // ---- K fragment global offsets (r7-verified) ----
    const int krow = ch * 32 + lr;
    const int csw  = krow & 7;
    int koff[4];
#pragma unroll
    for (int ks = 0; ks < 4; ++ks)
        koff[ks] = krow * 256 + (((ks * 4 + lg) ^ csw) << 4);
    const char* kbb = (const char*)kb + (((size_t)(b * 32)) << 14);

    // ============ pass A: barrier-free masked row sums (r7/r8 proven) ============
    float lsum[4] = {0.f, 0.f, 0.f, 0.f};
#pragma unroll 2
    for (int kt = 0; kt < NT; ++kt) {
        const char* tp = kbb + ((size_t)kt << 14);
        bfv8 kf0[4], kf1[4];
#pragma unroll
        for (int ks = 0; ks < 4; ++ks) {
            kf0[ks] = *(const bfv8*)(tp + koff[ks]);
            kf1[ks] = *(const bfv8*)(tp + koff[ks] + 4096);
        }
        f32x4 acc0 = {0.f, 0.f, 0.f, 0.f}, acc1 = {0.f, 0.f, 0.f, 0.f};
#pragma unroll
        for (int ks = 0; ks < 4; ++ks) {
            acc0 = mfma16(qa[ks], kf0[ks], acc0);
            acc1 = mfma16(qa[ks], kf1[ks], acc1);
        }

        const int j0 = kt * BK + ch * 32 + lr;
        const int j1 = j0 + 16;
        const bool vj0 = (vm0 >> kt) & 1;
        const bool vj1 = (vm1 >> kt) & 1;
#pragma unroll
        for (int r = 0; r < 4; ++r) {
            const int i = i_r[r];
            const float p0 = (bi[r] && vj0 && (j0 < i))
                ? __expf(acc0[r] * INV_SQRT_D - (float)(i - j0)) : 0.f;
            const float p1 = (bi[r] && vj1 && (j1 < i))
                ? __expf(acc1[r] * INV_SQRT_D - (float)(i - j1)) : 0.f;
            lsum[r] += p0 + p1;
        }
    }

    // ---- reduce row sums ----
#pragma unroll
    for (int r = 0; r < 4; ++r) {
        lsum[r] += __shfl_xor(lsum[r], 1);
        lsum[r] += __shfl_xor(lsum[r], 2);
        lsum[r] += __shfl_xor(lsum[r], 4);
        lsum[r] += __shfl_xor(lsum[r], 8);
    }
    if (lr == 0) {
#pragma unroll
        for (int r = 0; r < 4; ++r) redsum[rg][ch][lg * 4 + r] = lsum[r];
    }

    // prefetch pass-B K(0) fragments into registers (in flight across reduce barriers)
    bfv8 kc0[4], kc1[4];
#pragma unroll
    for (int ks = 0; ks < 4; ++ks) {
        kc0[ks] = *(const bfv8*)(kbb + koff[ks]);
        kc1[ks] = *(const bfv8*)(kbb + koff[ks] + 4096);
    }

    __syncthreads();
    if (tid < BQ) {
        const float s = redsum[tid >> 4][0][tid & 15] + redsum[tid >> 4][1][tid & 15];
        dinv_lds[tid] = 1.f / (s + ((s == 0.f) ? 1.f : 0.f) + 1e-20f);
    }
    __syncthreads();

    float dinv[4];
#pragma unroll
    for (int r = 0; r < 4; ++r) dinv[r] = dinv_lds[rg * 16 + lg * 4 + r];

    // ============ pass B: K in regs (prefetched), V staged, r8 barrier scheme ============
    f32x4 oacc[4];
#pragma unroll
    for (int nf = 0; nf < 4; ++nf) oacc[nf] = (f32x4){0.f, 0.f, 0.f, 0.f};

    const int arow = tid >> 3;
    const int ac   = (tid & 7) * 8;

    for (int kt = 0; kt < NT; ++kt) {
        // issue V(kt+1) staging FIRST (oldest 4 in vmcnt queue)
        if (kt + 1 < NT) stageV(kt + 1, (kt + 1) & 1);

        // QK(kt) from registers (landed; prefetched a full iteration ago)
        f32x4 acc0 = {0.f, 0.f, 0.f, 0.f}, acc1 = {0.f, 0.f, 0.f, 0.f};
#pragma unroll
        for (int ks = 0; ks < 4; ++ks) {
            acc0 = mfma16(qa[ks], kc0[ks], acc0);
            acc1 = mfma16(qa[ks], kc1[ks], acc1);
        }

        const int j0 = kt * BK + ch * 32 + lr;
        const int j1 = j0 + 16;
        const bool vj0 = (vm0 >> kt) & 1;
        const bool vj1 = (vm1 >> kt) & 1;
#pragma unroll
        for (int r = 0; r < 4; ++r) {
            const int i = i_r[r];
            const float p0 = (bi[r] && vj0 && (j0 < i))
                ? __expf(acc0[r] * INV_SQRT_D - (float)(i - j0)) * dinv[r] : 0.f;
            const float p1 = (bi[r] && vj1 && (j1 < i))
                ? __expf(acc1[r] * INV_SQRT_D - (float)(i - j1)) * dinv[r] : 0.f;
            ps[rg * 16 + lg * 4 + r][ch * 32 + lr]      = (__bf16)p0;
            ps[rg * 16 + lg * 4 + r][ch * 32 + 16 + lr] = (__bf16)p1;
        }

        // prefetch K(kt+1) fragments (8 loads; after stageV, before stores)
        if (kt + 1 < NT) {
            const char* tp = kbb + ((size_t)(kt + 1) << 14);
#pragma unroll
            for (int ks = 0; ks < 4; ++ks) {
                kc0[ks] = *(const bfv8*)(tp + koff[ks]);
                kc1[ks] = *(const bfv8*)(tp + koff[ks] + 4096);
            }
        }

        // mid barrier: publish ps; vmcnt stays in flight
        asm volatile("s_waitcnt lgkmcnt(0)" ::: "memory");
        __builtin_amdgcn_s_barrier();
        asm volatile("" ::: "memory");

        // coalesced attn tile store from ps (2 stores, newest in queue)
        {
            const bfv8 t = *(const bfv8*)&ps[arow][ac];
            float4 f0, f1;
            f0.x = (float)t[0]; f0.y = (float)t[1]; f0.z = (float)t[2]; f0.w = (float)t[3];
            f1.x = (float)t[4]; f1.y = (float)t[5]; f1.z = (float)t[6]; f1.w = (float)t[7];
            float* ap = &attn[((size_t)(b * S + i0 + arow)) * S + kt * BK + ac];
            *(float4*)ap = f0;
            *(float4*)(ap + 4) = f1;
        }

        // PV(kt): P from LDS, V from staged vslot[kt&1]
#pragma unroll
        for (int ks = 0; ks < 2; ++ks) {
            const bfv8 pa = *(const bfv8*)&ps[rg * 16 + lr][ks * 32 + lg * 8];
#pragma unroll
            for (int nf = 0; nf < 4; ++nf) {
                const bfv8 vf = vfrag(kt & 1, ch * 64 + nf * 16 + lr, ks * 4 + lg);
                oacc[nf] = mfma16(pa, vf, oacc[nf]);
            }
        }

        // end barrier: retire stageV(kt+1) (4 oldest); kc loads (8) + stores (2) stay in flight
        asm volatile("s_waitcnt vmcnt(10)" ::: "memory");
        __builtin_amdgcn_s_barrier();
        asm volatile("" ::: "memory");
    }

    // ---- write out ----
#pragma unroll
    for (int nf = 0; nf < 4; ++nf)
#pragma unroll
        for (int r = 0; r < 4; ++r)
            out[((size_t)(b * S + i_r[r])) * D + ch * 64 + nf * 16 + lr] = oacc[nf][r];

    // ---- zero-fill attn tiles above the block diagonal ----
    const int zt = NKT - NT;
    const float4 z4 = make_float4(0.f, 0.f, 0.f, 0.f);
    for (int u = tid; u < zt * 512; u += 256) {
        const int t   = u >> 9;
        const int rem = u & 511;
        const int row = rem >> 4;
        const int c4  = rem & 15;
        *(float4*)&attn[((size_t)(b * S + i0 + row)) * S + (NT + t) * BK + c4 * 4] = z4;
    }
}

// ============ fallback (proven) if ws too small ============
__global__ __launch_bounds__(256) void attn_kernel_fb(
    const float* __restrict__ q, const float* __restrict__ k,
    const float* __restrict__ v, const float* __restrict__ rep,
    float* __restrict__ out, float* __restrict__ attn)
{
    __shared__ __attribute__((aligned(16))) __bf16 qs [BQ][136];
    __shared__ __attribute__((aligned(16))) __bf16 ksm[BK][136];
    __shared__ __attribute__((aligned(16))) __bf16 vsT[D][72];
    __shared__ __attribute__((aligned(16))) __bf16 psl[BQ][72];
    __shared__ float redsum[2][2][16];
    __shared__ float dinv_lds[BQ];

    const int tid  = threadIdx.x;
    const int bid  = blockIdx.x;
    const int b    = bid & 7;
    const int qt   = (NQT - 1) - (bid >> 3);
    const int i0   = qt * BQ;
    const int NT   = ((qt * BQ + (BQ - 2)) >> 6) + 1;

    const int lane = tid & 63;
    const int w    = tid >> 6;
    const int rg   = w >> 1;
    const int ch   = w & 1;
    const int lr   = lane & 15;
    const int lg   = lane >> 4;

    for (int c = tid; c < BQ * 16; c += 256) {
        const int row = c >> 4, c8 = c & 15;
        const float4 f0 = *(const float4*)&q[((size_t)(b * S + i0 + row)) * D + c8 * 8];
        const float4 f1 = *(const float4*)&q[((size_t)(b * S + i0 + row)) * D + c8 * 8 + 4];
        bfv8 t;
        t[0] = (__bf16)f0.x; t[1] = (__bf16)f0.y; t[2] = (__bf16)f0.z; t[3] = (__bf16)f0.w;
        t[4] = (__bf16)f1.x; t[5] = (__bf16)f1.y; t[6] = (__bf16)f1.z; t[7] = (__bf16)f1.w;
        *(bfv8*)&qs[row][c8 * 8] = t;
    }
    __syncthreads();

    bfv8 qa[4];
#pragma unroll
    for (int ks = 0; ks < 4; ++ks)
        qa[ks] = *(const bfv8*)&qs[rg * 16 + lr][ks * 32 + lg * 8];

    int  i_r[4];
    bool bi[4];
#pragma unroll
    for (int r = 0; r < 4; ++r) {
        i_r[r] = i0 + rg * 16 + lg * 4 + r;
        bi[r]  = rep[(size_t)b * S + i_r[r]] > 0.5f;
    }

    float lsum[4] = {0.f, 0.f, 0.f, 0.f};
    for (int kt = 0; kt < NT; ++kt) {
        __syncthreads();
        for (int c = tid; c < BK * 16; c += 256) {
            const int row = c >> 4, c8 = c & 15;
            const float4 f0 = *(const float4*)&k[((size_t)(b * S + kt * BK + row)) * D + c8 * 8];
            const float4 f1 = *(const float4*)&k[((size_t)(b * S + kt * BK + row)) * D + c8 * 8 + 4];
            bfv8 t;
            t[0] = (__bf16)f0.x; t[1] = (__bf16)f0.y; t[2] = (__bf16)f0.z; t[3] = (__bf16)f0.w;
            t[4] = (__bf16)f1.x; t[5] = (__bf16)f1.y; t[6] = (__bf16)f1.z; t[7] = (__bf16)f1.w;
            *(bfv8*)&ksm[row][c8 * 8] = t;
        }
        __syncthreads();

        f32x4 acc0 = {0.f, 0.f, 0.f, 0.f}, acc1 = {0.f, 0.f, 0.f, 0.f};
#pragma unroll
        for (int ks = 0; ks < 4; ++ks) {
            const bfv8 b0 = *(const bfv8*)&ksm[ch * 32 + lr][ks * 32 + lg * 8];
            const bfv8 b1 = *(const bfv8*)&ksm[ch * 32 + 16 + lr][ks * 32 + lg * 8];
            acc0 = mfma16(qa[ks], b0, acc0);
            acc1 = mfma16(qa[ks], b1, acc1);
        }
        const int j0 = kt * BK + ch * 32 + lr;
        const int j1 = j0 + 16;
        const bool vj0 = rep[(size_t)b * S + j0] > 0.5f;
        const bool vj1 = rep[(size_t)b * S + j1] > 0.5f;
#pragma unroll
        for (int r = 0; r < 4; ++r) {
            const int i = i_r[r];
            const float p0 = (bi[r] && vj0 && (j0 < i))
                ? __expf(acc0[r] * INV_SQRT_D - (float)(i - j0)) : 0.f;
            const float p1 = (bi[r] && vj1 && (j1 < i))
                ? __expf(acc1[r] * INV_SQRT_D - (float)(i - j1)) : 0.f;
            lsum[r] += p0 + p1;
        }
    }

#pragma unroll
    for (int r = 0; r < 4; ++r) {
        lsum[r] += __shfl_xor(lsum[r], 1);
        lsum[r] += __shfl_xor(lsum[r], 2);
        lsum[r] += __shfl_xor(lsum[r], 4);
        lsum[r] += __shfl_xor(lsum[r], 8);
    }
    if (lr == 0) {
#pragma unroll
        for (int r = 0; r < 4; ++r) redsum[rg][ch][lg * 4 + r] = lsum[r];
    }
    __syncthreads();
    if (tid < BQ) {
        const float s = redsum[tid >> 4][0][tid & 15] + redsum[tid >> 4][1][tid & 15];
        dinv_lds[tid] = 1.f / (s + ((s == 0.f) ? 1.f : 0.f) + 1e-20f);
    }
    __syncthreads();

    float dinv[4];
#pragma unroll
    for (int r = 0; r < 4; ++r) dinv[r] = dinv_lds[rg * 16 + lg * 4 + r];

    f32x4 oacc[4];
#pragma unroll
    for (int nf = 0; nf < 4; ++nf) oacc[nf] = (f32x4){0.f, 0.f, 0.f, 0.f};

    for (int kt = 0; kt < NT; ++kt) {
        __syncthreads();
        for (int c = tid; c < BK * 16; c += 256) {
            const int row = c >> 4, c8 = c & 15;
            const float4 f0 = *(const float4*)&k[((size_t)(b * S + kt * BK + row)) * D + c8 * 8];
            const float4 f1 = *(const float4*)&k[((size_t)(b * S + kt * BK + row)) * D + c8 * 8 + 4];
            bfv8 t;
            t[0] = (__bf16)f0.x; t[1] = (__bf16)f0.y; t[2] = (__bf16)f0.z; t[3] = (__bf16)f0.w;
            t[4] = (__bf16)f1.x; t[5] = (__bf16)f1.y; t[6] = (__bf16)f1.z; t[7] = (__bf16)f1.w;
            *(bfv8*)&ksm[row][c8 * 8] = t;
        }
        for (int u = tid; u < 1024; u += 256) {
            const int p  = u & 31;
            const int dq = u >> 5;
            const float4 va = *(const float4*)&v[((size_t)(b * S + kt * BK + 2 * p)) * D + dq * 4];
            const float4 vb = *(const float4*)&v[((size_t)(b * S + kt * BK + 2 * p + 1)) * D + dq * 4];
            *(unsigned int*)&vsT[dq * 4 + 0][2 * p] = pack2(va.x, vb.x);
            *(unsigned int*)&vsT[dq * 4 + 1][2 * p] = pack2(va.y, vb.y);
            *(unsigned int*)&vsT[dq * 4 + 2][2 * p] = pack2(va.z, vb.z);
            *(unsigned int*)&vsT[dq * 4 + 3][2 * p] = pack2(va.w, vb.w);
        }
        __syncthreads();

        f32x4 acc0 = {0.f, 0.f, 0.f, 0.f}, acc1 = {0.f, 0.f, 0.f, 0.f};
#pragma unroll
        for (int ks = 0; ks < 4; ++ks) {
            const bfv8 b0 = *(const bfv8*)&ksm[ch * 32 + lr][ks * 32 + lg * 8];
            const bfv8 b1 = *(const bfv8*)&ksm[ch * 32 + 16 + lr][ks * 32 + lg * 8];
            acc0 = mfma16(qa[ks], b0, acc0);
            acc1 = mfma16(qa[ks], b1, acc1);
        }
        const int j0 = kt * BK + ch * 32 + lr;
        const int j1 = j0 + 16;
        const bool vj0 = rep[(size_t)b * S + j0] > 0.5f;
        const bool vj1 = rep[(size_t)b * S + j1] > 0.5f;
#pragma unroll
        for (int r = 0; r < 4; ++r) {
            const int i = i_r[r];
            const float p0 = (bi[r] && vj0 && (j0 < i))
                ? __expf(acc0[r] * INV_SQRT_D - (float)(i - j0)) * dinv[r] : 0.f;
            const float p1 = (bi[r] && vj1 && (j1 < i))
                ? __expf(acc1[r] * INV_SQRT_D - (float)(i - j1)) * dinv[r] : 0.f;
            attn[((size_t)(b * S + i)) * S + j0] = p0;
            attn[((size_t)(b * S + i)) * S + j1] = p1;
            psl[rg * 16 + lg * 4 + r][ch * 32 + lr]      = (__bf16)p0;
            psl[rg * 16 + lg * 4 + r][ch * 32 + 16 + lr] = (__bf16)p1;
        }
        __syncthreads();

#pragma unroll
        for (int ks = 0; ks < 2; ++ks) {
            const bfv8 pa = *(const bfv8*)&psl[rg * 16 + lr][ks * 32 + lg * 8];
#pragma unroll
            for (int nf = 0; nf < 4; ++nf) {
                const bfv8 vf = *(const bfv8*)&vsT[ch * 64 + nf * 16 + lr][ks * 32 + lg * 8];
                oacc[nf] = mfma16(pa, vf, oacc[nf]);
            }
        }
    }

#pragma unroll
    for (int nf = 0; nf < 4; ++nf)
#pragma unroll
        for (int r = 0; r < 4; ++r)
            out[((size_t)(b * S + i_r[r])) * D + ch * 64 + nf * 16 + lr] = oacc[nf][r];

    const int zt = NKT - NT;
    const float4 z4 = make_float4(0.f, 0.f, 0.f, 0.f);
    for (int u = tid; u < zt * 512; u += 256) {
        const int t   = u >> 9;
        const int rem = u & 511;
        const int row = rem >> 4;
        const int c4  = rem & 15;
        *(float4*)&attn[((size_t)(b * S + i0 + row)) * S + (NT + t) * BK + c4 * 4] = z4;
    }
}

extern "C" void kernel_launch(void* const* d_in, const int* in_sizes, int n_in,
                              void* d_out, int out_size, void* d_ws, size_t ws_size,
                              hipStream_t stream)
{
    const float* q   = (const float*)d_in[0];
    const float* k   = (const float*)d_in[1];
    const float* v   = (const float*)d_in[2];
    const float* rep = (const float*)d_in[3];
    float* out  = (float*)d_out;
    float* attn = out + (size_t)NBATCH * S * D;

    const size_t kb_elems = (size_t)NBATCH * S * D;   // bf16 elems (4MB each buf)
    const size_t need     = kb_elems * 2 * 2;         // kb + vtb bytes = 16.78 MB

    if (ws_size < need) {
        hipLaunchKernelGGL(attn_kernel_fb, dim3(NBATCH * NQT), dim3(256), 0, stream,
                           q, k, v, rep, out, attn);
        return;
    }

    __bf16* kb  = (__bf16*)d_ws;
    __bf16* vtb = kb + kb_elems;

    hipLaunchKernelGGL(prep_kernel, dim3(1280), dim3(256), 0, stream, k, v, kb, vtb);
    hipLaunchKernelGGL(attn_hybrid, dim3(NBATCH * NQT), dim3(256), 0, stream,
                       q, rep, kb, vtb, out, attn);
}

// Round 13
// 60.466 us; speedup vs baseline: 1.2790x; 1.1892x over previous
//
#include <hip/hip_runtime.h>

#define NBATCH 8
#define S 2048
#define D 128
#define BQ 32
#define BK 64
#define NKT 32
#define NQT 64
#define INV_SQRT_D 0.08838834764831845f

typedef __bf16 bfv8 __attribute__((ext_vector_type(8)));
typedef float f32x4 __attribute__((ext_vector_type(4)));

__device__ __forceinline__ f32x4 mfma16(bfv8 a, bfv8 b, f32x4 c) {
    return __builtin_amdgcn_mfma_f32_16x16x32_bf16(a, b, c, 0, 0, 0);
}

__device__ __forceinline__ unsigned int pack2(float lo, float hi) {
    unsigned short a = __builtin_bit_cast(unsigned short, (__bf16)lo);
    unsigned short b = __builtin_bit_cast(unsigned short, (__bf16)hi);
    return (unsigned int)a | ((unsigned int)b << 16);
}

__device__ __forceinline__ void gload_lds16(const void* g, void* l) {
    __builtin_amdgcn_global_load_lds(
        (const __attribute__((address_space(1))) unsigned int*)g,
        (__attribute__((address_space(3))) unsigned int*)l, 16, 0, 0);
}

// ============ prep: K -> bf16 swizzled tiles; V -> bf16 transposed swizzled ============
__global__ __launch_bounds__(256) void prep_kernel(
    const float* __restrict__ k, const float* __restrict__ v,
    __bf16* __restrict__ kb, __bf16* __restrict__ vtb)
{
    __shared__ __bf16 lds[64][132];
    const int bidx = blockIdx.x;
    const int tid  = threadIdx.x;

    if (bidx < 1024) {                 // K part: fully coalesced
        const int t   = bidx * 256 + tid;
        const int b   = t >> 15;
        const int kt  = (t >> 10) & 31;
        const int row = (t >> 4) & 63;
        const int u   = t & 15;
        const float4 f0 = *(const float4*)&k[((size_t)(b * S + kt * 64 + row)) * D + u * 8];
        const float4 f1 = *(const float4*)&k[((size_t)(b * S + kt * 64 + row)) * D + u * 8 + 4];
        bfv8 o;
        o[0] = (__bf16)f0.x; o[1] = (__bf16)f0.y; o[2] = (__bf16)f0.z; o[3] = (__bf16)f0.w;
        o[4] = (__bf16)f1.x; o[5] = (__bf16)f1.y; o[6] = (__bf16)f1.z; o[7] = (__bf16)f1.w;
        const size_t unit = ((size_t)((b * 32 + kt) * 64 + row)) * 16 + (u ^ (row & 7));
        *(bfv8*)&kb[unit * 8] = o;
    } else {                           // V part: LDS-staged transpose
        const int vb = bidx - 1024;
        const int b  = vb >> 5;
        const int kt = vb & 31;
#pragma unroll
        for (int p = 0; p < 8; ++p) {
            const int idx = p * 256 + tid;
            const int kv  = idx >> 5;
            const int c4  = idx & 31;
            const float4 f = *(const float4*)&v[((size_t)(b * S + kt * 64 + kv)) * D + c4 * 4];
            __bf16* dst = &lds[kv][c4 * 4];
            dst[0] = (__bf16)f.x; dst[1] = (__bf16)f.y; dst[2] = (__bf16)f.z; dst[3] = (__bf16)f.w;
        }
        __syncthreads();
#pragma unroll
        for (int p = 0; p < 4; ++p) {
            const int idx = p * 256 + tid;
            const int d   = idx >> 3;
            const int u   = idx & 7;
            bfv8 o;
#pragma unroll
            for (int j = 0; j < 8; ++j) o[j] = lds[u * 8 + j][d];
            const size_t unit = ((size_t)((b * 32 + kt) * 128 + d)) * 8 + (u ^ (d & 7));
            *(bfv8*)&vtb[unit * 8] = o;
        }
    }
}

// ============ main: 512-thread producer/consumer pipeline (16 waves/CU) ============
// pass A: 8 waves split kt even/odd (barrier-free, K direct from global).
// pass B: waves 0-3 produce P (QK from reg-prefetched K, exp); waves 4-7 consume
//         (PV from gload_lds-staged V, attn stores, O accumulate). 1 barrier/iter.
__global__ __launch_bounds__(512) void attn_pc(
    const float* __restrict__ q, const float* __restrict__ rep,
    const __bf16* __restrict__ kb, const __bf16* __restrict__ vtb,
    float* __restrict__ out, float* __restrict__ attn)
{
    __shared__ __attribute__((aligned(16))) __bf16 vslot[2][8192];  // 32KB
    __shared__ __attribute__((aligned(16))) __bf16 qs[BQ][136];     // 8.7KB
    __shared__ __attribute__((aligned(16))) __bf16 ps[2][BQ][72];   // 9.2KB
    __shared__ float redsum[2][2][2][16];                           // [gp][rg][ch]
    __shared__ float dinv_lds[BQ];

    const int tid = threadIdx.x;
    const int bid = blockIdx.x;
    const int b   = bid & 7;
    const int g   = bid >> 3;
    // balanced pairing (r8 proven): CU gets qt pair (63-g, g)
    const int qt  = (g < 32) ? (63 - g) : (g - 32);
    const int i0  = qt * BQ;
    const int NT  = ((qt * BQ + (BQ - 2)) >> 6) + 1;

    const int gp   = tid >> 8;        // pass A: kt parity; pass B: 0=producer 1=consumer
    const int gtid = tid & 255;
    const int gw   = gtid >> 6;       // wave within group 0..3
    const int lane = tid & 63;
    const int rg   = gw >> 1;
    const int ch   = gw & 1;
    const int lr   = lane & 15;
    const int lg   = lane >> 4;

    auto stageV = [&](int kt, int slot) {
        const char* src = (const char*)vtb + (((size_t)(b * 32 + kt)) << 14);
        char* dst = (char*)&vslot[slot][0];
#pragma unroll
        for (int i2 = 0; i2 < 4; ++i2) {
            const int n0 = (gw * 4 + i2) * 64;
            gload_lds16(src + (size_t)(n0 + lane) * 16, dst + (size_t)n0 * 16);
        }
    };
    auto vfrag = [&](int slot, int drow, int u) -> bfv8 {
        return *(const bfv8*)&vslot[slot][(drow * 8 + (u ^ (drow & 7))) * 8];
    };

    // ---- prologue: consumer group issues V(0) (lands during pass A) ----
    if (gp == 1) stageV(0, 0);

    // stage Q -> bf16 LDS: 512 threads, exactly one bfv8 each
    {
        const int row = tid >> 4, c8 = tid & 15;
        const float4 f0 = *(const float4*)&q[((size_t)(b * S + i0 + row)) * D + c8 * 8];
        const float4 f1 = *(const float4*)&q[((size_t)(b * S + i0 + row)) * D + c8 * 8 + 4];
        bfv8 t;
        t[0] = (__bf16)f0.x; t[1] = (__bf16)f0.y; t[2] = (__bf16)f0.z; t[3] = (__bf16)f0.w;
        t[4] = (__bf16)f1.x; t[5] = (__bf16)f1.y; t[6] = (__bf16)f1.z; t[7] = (__bf16)f1.w;
        *(bfv8*)&qs[row][c8 * 8] = t;
    }

    // per-lane column-validity bitmasks
    unsigned int vm0 = 0, vm1 = 0;
    for (int kt = 0; kt < NT; ++kt) {
        const unsigned int t0 = (rep[(size_t)b * S + kt * BK + ch * 32 + lr]      > 0.5f) ? 1u : 0u;
        const unsigned int t1 = (rep[(size_t)b * S + kt * BK + ch * 32 + 16 + lr] > 0.5f) ? 1u : 0u;
        vm0 |= t0 << kt;
        vm1 |= t1 << kt;
    }

    int  i_r[4];
    bool bi[4];
#pragma unroll
    for (int r = 0; r < 4; ++r) {
        i_r[r] = i0 + rg * 16 + lg * 4 + r;
        bi[r]  = rep[(size_t)b * S + i_r[r]] > 0.5f;
    }
    __syncthreads();   // qs ready; V(0) drained

    bfv8 qa[4];
#pragma unroll
    for (int ks = 0; ks < 4; ++ks)
        qa[ks] = *(const bfv8*)&qs[rg * 16 + lr][ks * 32 + lg * 8];

    // ---- K fragment global offsets (r7-verified) ----
    const int krow = ch * 32 + lr;
    const int csw  = krow & 7;
    int koff[4];
#pragma unroll
    for (int ks = 0; ks < 4; ++ks)
        koff[ks] = krow * 256 + (((ks * 4 + lg) ^ csw) << 4);
    const char* kbb = (const char*)kb + (((size_t)(b * 32)) << 14);

    // ============ pass A: barrier-free, groups split kt even/odd ============
    float lsum[4] = {0.f, 0.f, 0.f, 0.f};
    for (int kt = gp; kt < NT; kt += 2) {
        const char* tp = kbb + ((size_t)kt << 14);
        bfv8 kf0[4], kf1[4];
#pragma unroll
        for (int ks = 0; ks < 4; ++ks) {
            kf0[ks] = *(const bfv8*)(tp + koff[ks]);
            kf1[ks] = *(const bfv8*)(tp + koff[ks] + 4096);
        }
        f32x4 acc0 = {0.f, 0.f, 0.f, 0.f}, acc1 = {0.f, 0.f, 0.f, 0.f};
#pragma unroll
        for (int ks = 0; ks < 4; ++ks) {
            acc0 = mfma16(qa[ks], kf0[ks], acc0);
            acc1 = mfma16(qa[ks], kf1[ks], acc1);
        }

        const int j0 = kt * BK + ch * 32 + lr;
        const int j1 = j0 + 16;
        const bool vj0 = (vm0 >> kt) & 1;
        const bool vj1 = (vm1 >> kt) & 1;
#pragma unroll
        for (int r = 0; r < 4; ++r) {
            const int i = i_r[r];
            const float p0 = (bi[r] && vj0 && (j0 < i))
                ? __expf(acc0[r] * INV_SQRT_D - (float)(i - j0)) : 0.f;
            const float p1 = (bi[r] && vj1 && (j1 < i))
                ? __expf(acc1[r] * INV_SQRT_D - (float)(i - j1)) : 0.f;
            lsum[r] += p0 + p1;
        }
    }

    // ---- reduce row sums (now with group axis) ----
#pragma unroll
    for (int r = 0; r < 4; ++r) {
        lsum[r] += __shfl_xor(lsum[r], 1);
        lsum[r] += __shfl_xor(lsum[r], 2);
        lsum[r] += __shfl_xor(lsum[r], 4);
        lsum[r] += __shfl_xor(lsum[r], 8);
    }
    if (lr == 0) {
#pragma unroll
        for (int r = 0; r < 4; ++r) redsum[gp][rg][ch][lg * 4 + r] = lsum[r];
    }

    // producer prefetches K(0) fragments (in flight across reduce barriers)
    bfv8 kc0[4], kc1[4];
    if (gp == 0) {
#pragma unroll
        for (int ks = 0; ks < 4; ++ks) {
            kc0[ks] = *(const bfv8*)(kbb + koff[ks]);
            kc1[ks] = *(const bfv8*)(kbb + koff[ks] + 4096);
        }
    }

    __syncthreads();
    if (tid < BQ) {
        const float s = redsum[0][tid >> 4][0][tid & 15] + redsum[0][tid >> 4][1][tid & 15]
                      + redsum[1][tid >> 4][0][tid & 15] + redsum[1][tid >> 4][1][tid & 15];
        dinv_lds[tid] = 1.f / (s + ((s == 0.f) ? 1.f : 0.f) + 1e-20f);
    }
    __syncthreads();

    float dinv[4];
#pragma unroll
    for (int r = 0; r < 4; ++r) dinv[r] = dinv_lds[rg * 16 + lg * 4 + r];

    // ============ pass B: producer/consumer pipeline, 1 barrier/iter ============
    f32x4 oacc[4];
#pragma unroll
    for (int nf = 0; nf < 4; ++nf) oacc[nf] = (f32x4){0.f, 0.f, 0.f, 0.f};

    const int arow = gtid >> 3;
    const int ac   = (gtid & 7) * 8;

    for (int kt = 0; kt < NT; ++kt) {
        if (gp == 0) {
            // ---- producer: QK(kt) from registers, exp, publish ps[kt&1] ----
            f32x4 acc0 = {0.f, 0.f, 0.f, 0.f}, acc1 = {0.f, 0.f, 0.f, 0.f};
#pragma unroll
            for (int ks = 0; ks < 4; ++ks) {
                acc0 = mfma16(qa[ks], kc0[ks], acc0);
                acc1 = mfma16(qa[ks], kc1[ks], acc1);
            }

            const int j0 = kt * BK + ch * 32 + lr;
            const int j1 = j0 + 16;
            const bool vj0 = (vm0 >> kt) & 1;
            const bool vj1 = (vm1 >> kt) & 1;
#pragma unroll
            for (int r = 0; r < 4; ++r) {
                const int i = i_r[r];
                const float p0 = (bi[r] && vj0 && (j0 < i))
                    ? __expf(acc0[r] * INV_SQRT_D - (float)(i - j0)) * dinv[r] : 0.f;
                const float p1 = (bi[r] && vj1 && (j1 < i))
                    ? __expf(acc1[r] * INV_SQRT_D - (float)(i - j1)) * dinv[r] : 0.f;
                ps[kt & 1][rg * 16 + lg * 4 + r][ch * 32 + lr]      = (__bf16)p0;
                ps[kt & 1][rg * 16 + lg * 4 + r][ch * 32 + 16 + lr] = (__bf16)p1;
            }

            // prefetch K(kt+1) fragments
            if (kt + 1 < NT) {
                const char* tp = kbb + ((size_t)(kt + 1) << 14);
#pragma unroll
                for (int ks = 0; ks < 4; ++ks) {
                    kc0[ks] = *(const bfv8*)(tp + koff[ks]);
                    kc1[ks] = *(const bfv8*)(tp + koff[ks] + 4096);
                }
            }
            asm volatile("s_waitcnt lgkmcnt(0)" ::: "memory");   // ps writes visible
        } else {
            // ---- consumer: stage V(kt); PV(kt-1); attn(kt-1) ----
            if (kt >= 1) {
                stageV(kt, kt & 1);

                const int pp = (kt - 1) & 1;
#pragma unroll
                for (int ks = 0; ks < 2; ++ks) {
                    const bfv8 pa = *(const bfv8*)&ps[pp][rg * 16 + lr][ks * 32 + lg * 8];
#pragma unroll
                    for (int nf = 0; nf < 4; ++nf) {
                        const bfv8 vf = vfrag(pp, ch * 64 + nf * 16 + lr, ks * 4 + lg);
                        oacc[nf] = mfma16(pa, vf, oacc[nf]);
                    }
                }

                // coalesced attn tile store (newest in vmem queue, stays in flight)
                const bfv8 t = *(const bfv8*)&ps[pp][arow][ac];
                float4 f0, f1;
                f0.x = (float)t[0]; f0.y = (float)t[1]; f0.z = (float)t[2]; f0.w = (float)t[3];
                f1.x = (float)t[4]; f1.y = (float)t[5]; f1.z = (float)t[6]; f1.w = (float)t[7];
                float* ap = &attn[((size_t)(b * S + i0 + arow)) * S + (kt - 1) * BK + ac];
                *(float4*)ap = f0;
                *(float4*)(ap + 4) = f1;

                // retire stageV(kt) (older) so next iter can read; attn stores stay in flight
                asm volatile("s_waitcnt vmcnt(2)" ::: "memory");
            }
        }
        __builtin_amdgcn_s_barrier();
        asm volatile("" ::: "memory");
    }

    // ============ epilogue ============
    if (gp == 1) {
        const int pp = (NT - 1) & 1;
#pragma unroll
        for (int ks = 0; ks < 2; ++ks) {
            const bfv8 pa = *(const bfv8*)&ps[pp][rg * 16 + lr][ks * 32 + lg * 8];
#pragma unroll
            for (int nf = 0; nf < 4; ++nf) {
                const bfv8 vf = vfrag(pp, ch * 64 + nf * 16 + lr, ks * 4 + lg);
                oacc[nf] = mfma16(pa, vf, oacc[nf]);
            }
        }
        {
            const bfv8 t = *(const bfv8*)&ps[pp][arow][ac];
            float4 f0, f1;
            f0.x = (float)t[0]; f0.y = (float)t[1]; f0.z = (float)t[2]; f0.w = (float)t[3];
            f1.x = (float)t[4]; f1.y = (float)t[5]; f1.z = (float)t[6]; f1.w = (float)t[7];
            float* ap = &attn[((size_t)(b * S + i0 + arow)) * S + (NT - 1) * BK + ac];
            *(float4*)ap = f0;
            *(float4*)(ap + 4) = f1;
        }
#pragma unroll
        for (int nf = 0; nf < 4; ++nf)
#pragma unroll
            for (int r = 0; r < 4; ++r)
                out[((size_t)(b * S + i_r[r])) * D + ch * 64 + nf * 16 + lr] = oacc[nf][r];
    } else {
        // producer group zero-fills attn tiles above the block diagonal
        const int zt = NKT - NT;
        const float4 z4 = make_float4(0.f, 0.f, 0.f, 0.f);
        for (int u = tid; u < zt * 512; u += 256) {
            const int t   = u >> 9;
            const int rem = u & 511;
            const int row = rem >> 4;
            const int c4  = rem & 15;
            *(float4*)&attn[((size_t)(b * S + i0 + row)) * S + (NT + t) * BK + c4 * 4] = z4;
        }
    }
}

// ============ fallback (proven) if ws too small ============
__global__ __launch_bounds__(256) void attn_kernel_fb(
    const float* __restrict__ q, const float* __restrict__ k,
    const float* __restrict__ v, const float* __restrict__ rep,
    float* __restrict__ out, float* __restrict__ attn)
{
    __shared__ __attribute__((aligned(16))) __bf16 qs [BQ][136];
    __shared__ __attribute__((aligned(16))) __bf16 ksm[BK][136];
    __shared__ __attribute__((aligned(16))) __bf16 vsT[D][72];
    __shared__ __attribute__((aligned(16))) __bf16 psl[BQ][72];
    __shared__ float redsum[2][2][16];
    __shared__ float dinv_lds[BQ];

    const int tid  = threadIdx.x;
    const int bid  = blockIdx.x;
    const int b    = bid & 7;
    const int qt   = (NQT - 1) - (bid >> 3);
    const int i0   = qt * BQ;
    const int NT   = ((qt * BQ + (BQ - 2)) >> 6) + 1;

    const int lane = tid & 63;
    const int w    = tid >> 6;
    const int rg   = w >> 1;
    const int ch   = w & 1;
    const int lr   = lane & 15;
    const int lg   = lane >> 4;

    for (int c = tid; c < BQ * 16; c += 256) {
        const int row = c >> 4, c8 = c & 15;
        const float4 f0 = *(const float4*)&q[((size_t)(b * S + i0 + row)) * D + c8 * 8];
        const float4 f1 = *(const float4*)&q[((size_t)(b * S + i0 + row)) * D + c8 * 8 + 4];
        bfv8 t;
        t[0] = (__bf16)f0.x; t[1] = (__bf16)f0.y; t[2] = (__bf16)f0.z; t[3] = (__bf16)f0.w;
        t[4] = (__bf16)f1.x; t[5] = (__bf16)f1.y; t[6] = (__bf16)f1.z; t[7] = (__bf16)f1.w;
        *(bfv8*)&qs[row][c8 * 8] = t;
    }
    __syncthreads();

    bfv8 qa[4];
#pragma unroll
    for (int ks = 0; ks < 4; ++ks)
        qa[ks] = *(const bfv8*)&qs[rg * 16 + lr][ks * 32 + lg * 8];

    int  i_r[4];
    bool bi[4];
#pragma unroll
    for (int r = 0; r < 4; ++r) {
        i_r[r] = i0 + rg * 16 + lg * 4 + r;
        bi[r]  = rep[(size_t)b * S + i_r[r]] > 0.5f;
    }

    float lsum[4] = {0.f, 0.f, 0.f, 0.f};
    for (int kt = 0; kt < NT; ++kt) {
        __syncthreads();
        for (int c = tid; c < BK * 16; c += 256) {
            const int row = c >> 4, c8 = c & 15;
            const float4 f0 = *(const float4*)&k[((size_t)(b * S + kt * BK + row)) * D + c8 * 8];
            const float4 f1 = *(const float4*)&k[((size_t)(b * S + kt * BK + row)) * D + c8 * 8 + 4];
            bfv8 t;
            t[0] = (__bf16)f0.x; t[1] = (__bf16)f0.y; t[2] = (__bf16)f0.z; t[3] = (__bf16)f0.w;
            t[4] = (__bf16)f1.x; t[5] = (__bf16)f1.y; t[6] = (__bf16)f1.z; t[7] = (__bf16)f1.w;
            *(bfv8*)&ksm[row][c8 * 8] = t;
        }
        __syncthreads();

        f32x4 acc0 = {0.f, 0.f, 0.f, 0.f}, acc1 = {0.f, 0.f, 0.f, 0.f};
#pragma unroll
        for (int ks = 0; ks < 4; ++ks) {
            const bfv8 b0 = *(const bfv8*)&ksm[ch * 32 + lr][ks * 32 + lg * 8];
            const bfv8 b1 = *(const bfv8*)&ksm[ch * 32 + 16 + lr][ks * 32 + lg * 8];
            acc0 = mfma16(qa[ks], b0, acc0);
            acc1 = mfma16(qa[ks], b1, acc1);
        }
        const int j0 = kt * BK + ch * 32 + lr;
        const int j1 = j0 + 16;
        const bool vj0 = rep[(size_t)b * S + j0] > 0.5f;
        const bool vj1 = rep[(size_t)b * S + j1] > 0.5f;
#pragma unroll
        for (int r = 0; r < 4; ++r) {
            const int i = i_r[r];
            const float p0 = (bi[r] && vj0 && (j0 < i))
                ? __expf(acc0[r] * INV_SQRT_D - (float)(i - j0)) : 0.f;
            const float p1 = (bi[r] && vj1 && (j1 < i))
                ? __expf(acc1[r] * INV_SQRT_D - (float)(i - j1)) : 0.f;
            lsum[r] += p0 + p1;
        }
    }

#pragma unroll
    for (int r = 0; r < 4; ++r) {
        lsum[r] += __shfl_xor(lsum[r], 1);
        lsum[r] += __shfl_xor(lsum[r], 2);
        lsum[r] += __shfl_xor(lsum[r], 4);
        lsum[r] += __shfl_xor(lsum[r], 8);
    }
    if (lr == 0) {
#pragma unroll
        for (int r = 0; r < 4; ++r) redsum[rg][ch][lg * 4 + r] = lsum[r];
    }
    __syncthreads();
    if (tid < BQ) {
        const float s = redsum[tid >> 4][0][tid & 15] + redsum[tid >> 4][1][tid & 15];
        dinv_lds[tid] = 1.f / (s + ((s == 0.f) ? 1.f : 0.f) + 1e-20f);
    }
    __syncthreads();

    float dinv[4];
#pragma unroll
    for (int r = 0; r < 4; ++r) dinv[r] = dinv_lds[rg * 16 + lg * 4 + r];

    f32x4 oacc[4];
#pragma unroll
    for (int nf = 0; nf < 4; ++nf) oacc[nf] = (f32x4){0.f, 0.f, 0.f, 0.f};

    for (int kt = 0; kt < NT; ++kt) {
        __syncthreads();
        for (int c = tid; c < BK * 16; c += 256) {
            const int row = c >> 4, c8 = c & 15;
            const float4 f0 = *(const float4*)&k[((size_t)(b * S + kt * BK + row)) * D + c8 * 8];
            const float4 f1 = *(const float4*)&k[((size_t)(b * S + kt * BK + row)) * D + c8 * 8 + 4];
            bfv8 t;
            t[0] = (__bf16)f0.x; t[1] = (__bf16)f0.y; t[2] = (__bf16)f0.z; t[3] = (__bf16)f0.w;
            t[4] = (__bf16)f1.x; t[5] = (__bf16)f1.y; t[6] = (__bf16)f1.z; t[7] = (__bf16)f1.w;
            *(bfv8*)&ksm[row][c8 * 8] = t;
        }
        for (int u = tid; u < 1024; u += 256) {
            const int p  = u & 31;
            const int dq = u >> 5;
            const float4 va = *(const float4*)&v[((size_t)(b * S + kt * BK + 2 * p)) * D + dq * 4];
            const float4 vb = *(const float4*)&v[((size_t)(b * S + kt * BK + 2 * p + 1)) * D + dq * 4];
            *(unsigned int*)&vsT[dq * 4 + 0][2 * p] = pack2(va.x, vb.x);
            *(unsigned int*)&vsT[dq * 4 + 1][2 * p] = pack2(va.y, vb.y);
            *(unsigned int*)&vsT[dq * 4 + 2][2 * p] = pack2(va.z, vb.z);
            *(unsigned int*)&vsT[dq * 4 + 3][2 * p] = pack2(va.w, vb.w);
        }
        __syncthreads();

        f32x4 acc0 = {0.f, 0.f, 0.f, 0.f}, acc1 = {0.f, 0.f, 0.f, 0.f};
#pragma unroll
        for (int ks = 0; ks < 4; ++ks) {
            const bfv8 b0 = *(const bfv8*)&ksm[ch * 32 + lr][ks * 32 + lg * 8];
            const bfv8 b1 = *(const bfv8*)&ksm[ch * 32 + 16 + lr][ks * 32 + lg * 8];
            acc0 = mfma16(qa[ks], b0, acc0);
            acc1 = mfma16(qa[ks], b1, acc1);
        }
        const int j0 = kt * BK + ch * 32 + lr;
        const int j1 = j0 + 16;
        const bool vj0 = rep[(size_t)b * S + j0] > 0.5f;
        const bool vj1 = rep[(size_t)b * S + j1] > 0.5f;
#pragma unroll
        for (int r = 0; r < 4; ++r) {
            const int i = i_r[r];
            const float p0 = (bi[r] && vj0 && (j0 < i))
                ? __expf(acc0[r] * INV_SQRT_D - (float)(i - j0)) * dinv[r] : 0.f;
            const float p1 = (bi[r] && vj1 && (j1 < i))
                ? __expf(acc1[r] * INV_SQRT_D - (float)(i - j1)) * dinv[r] : 0.f;
            attn[((size_t)(b * S + i)) * S + j0] = p0;
            attn[((size_t)(b * S + i)) * S + j1] = p1;
            psl[rg * 16 + lg * 4 + r][ch * 32 + lr]      = (__bf16)p0;
            psl[rg * 16 + lg * 4 + r][ch * 32 + 16 + lr] = (__bf16)p1;
        }
        __syncthreads();

#pragma unroll
        for (int ks = 0; ks < 2; ++ks) {
            const bfv8 pa = *(const bfv8*)&psl[rg * 16 + lr][ks * 32 + lg * 8];
#pragma unroll
            for (int nf = 0; nf < 4; ++nf) {
                const bfv8 vf = *(const bfv8*)&vsT[ch * 64 + nf * 16 + lr][ks * 32 + lg * 8];
                oacc[nf] = mfma16(pa, vf, oacc[nf]);
            }
        }
    }

#pragma unroll
    for (int nf = 0; nf < 4; ++nf)
#pragma unroll
        for (int r = 0; r < 4; ++r)
            out[((size_t)(b * S + i_r[r])) * D + ch * 64 + nf * 16 + lr] = oacc[nf][r];

    const int zt = NKT - NT;
    const float4 z4 = make_float4(0.f, 0.f, 0.f, 0.f);
    for (int u = tid; u < zt * 512; u += 256) {
        const int t   = u >> 9;
        const int rem = u & 511;
        const int row = rem >> 4;
        const int c4  = rem & 15;
        *(float4*)&attn[((size_t)(b * S + i0 + row)) * S + (NT + t) * BK + c4 * 4] = z4;
    }
}

extern "C" void kernel_launch(void* const* d_in, const int* in_sizes, int n_in,
                              void* d_out, int out_size, void* d_ws, size_t ws_size,
                              hipStream_t stream)
{
    const float* q   = (const float*)d_in[0];
    const float* k   = (const float*)d_in[1];
    const float* v   = (const float*)d_in[2];
    const float* rep = (const float*)d_in[3];
    float* out  = (float*)d_out;
    float* attn = out + (size_t)NBATCH * S * D;

    const size_t kb_elems = (size_t)NBATCH * S * D;   // bf16 elems (4MB each buf)
    const size_t need     = kb_elems * 2 * 2;         // kb + vtb bytes = 16.78 MB

    if (ws_size < need) {
        hipLaunchKernelGGL(attn_kernel_fb, dim3(NBATCH * NQT), dim3(256), 0, stream,
                           q, k, v, rep, out, attn);
        return;
    }

    __bf16* kb  = (__bf16*)d_ws;
    __bf16* vtb = kb + kb_elems;

    hipLaunchKernelGGL(prep_kernel, dim3(1280), dim3(256), 0, stream, k, v, kb, vtb);
    hipLaunchKernelGGL(attn_pc, dim3(NBATCH * NQT), dim3(512), 0, stream,
                       q, rep, kb, vtb, out, attn);
}

// Round 14
// 60.441 us; speedup vs baseline: 1.2795x; 1.0004x over previous
//
#include <hip/hip_runtime.h>

#define NBATCH 8
#define S 2048
#define D 128
#define BQ 32
#define BK 64
#define NKT 32
#define NQT 64
#define INV_SQRT_D 0.08838834764831845f

typedef __bf16 bfv8 __attribute__((ext_vector_type(8)));
typedef float f32x4 __attribute__((ext_vector_type(4)));

__device__ __forceinline__ f32x4 mfma16(bfv8 a, bfv8 b, f32x4 c) {
    return __builtin_amdgcn_mfma_f32_16x16x32_bf16(a, b, c, 0, 0, 0);
}

__device__ __forceinline__ unsigned int pack2(float lo, float hi) {
    unsigned short a = __builtin_bit_cast(unsigned short, (__bf16)lo);
    unsigned short b = __builtin_bit_cast(unsigned short, (__bf16)hi);
    return (unsigned int)a | ((unsigned int)b << 16);
}

__device__ __forceinline__ void gload_lds16(const void* g, void* l) {
    __builtin_amdgcn_global_load_lds(
        (const __attribute__((address_space(1))) unsigned int*)g,
        (__attribute__((address_space(3))) unsigned int*)l, 16, 0, 0);
}

// ============ prep: K -> bf16 swizzled tiles; V -> bf16 transposed swizzled ============
__global__ __launch_bounds__(256) void prep_kernel(
    const float* __restrict__ k, const float* __restrict__ v,
    __bf16* __restrict__ kb, __bf16* __restrict__ vtb)
{
    __shared__ __bf16 lds[64][132];
    const int bidx = blockIdx.x;
    const int tid  = threadIdx.x;

    if (bidx < 1024) {                 // K part: fully coalesced
        const int t   = bidx * 256 + tid;
        const int b   = t >> 15;
        const int kt  = (t >> 10) & 31;
        const int row = (t >> 4) & 63;
        const int u   = t & 15;
        const float4 f0 = *(const float4*)&k[((size_t)(b * S + kt * 64 + row)) * D + u * 8];
        const float4 f1 = *(const float4*)&k[((size_t)(b * S + kt * 64 + row)) * D + u * 8 + 4];
        bfv8 o;
        o[0] = (__bf16)f0.x; o[1] = (__bf16)f0.y; o[2] = (__bf16)f0.z; o[3] = (__bf16)f0.w;
        o[4] = (__bf16)f1.x; o[5] = (__bf16)f1.y; o[6] = (__bf16)f1.z; o[7] = (__bf16)f1.w;
        const size_t unit = ((size_t)((b * 32 + kt) * 64 + row)) * 16 + (u ^ (row & 7));
        *(bfv8*)&kb[unit * 8] = o;
    } else {                           // V part: LDS-staged transpose
        const int vb = bidx - 1024;
        const int b  = vb >> 5;
        const int kt = vb & 31;
#pragma unroll
        for (int p = 0; p < 8; ++p) {
            const int idx = p * 256 + tid;
            const int kv  = idx >> 5;
            const int c4  = idx & 31;
            const float4 f = *(const float4*)&v[((size_t)(b * S + kt * 64 + kv)) * D + c4 * 4];
            __bf16* dst = &lds[kv][c4 * 4];
            dst[0] = (__bf16)f.x; dst[1] = (__bf16)f.y; dst[2] = (__bf16)f.z; dst[3] = (__bf16)f.w;
        }
        __syncthreads();
#pragma unroll
        for (int p = 0; p < 4; ++p) {
            const int idx = p * 256 + tid;
            const int d   = idx >> 3;
            const int u   = idx & 7;
            bfv8 o;
#pragma unroll
            for (int j = 0; j < 8; ++j) o[j] = lds[u * 8 + j][d];
            const size_t unit = ((size_t)((b * 32 + kt) * 128 + d)) * 8 + (u ^ (d & 7));
            *(bfv8*)&vtb[unit * 8] = o;
        }
    }
}

// ============ main: 512-thread producer/consumer pipeline (16 waves/CU) ============
// r13 structure + three latency fixes: unroll-2 pass A; producer K-prefetch before exp;
// consumer stages V(kt+1) with 3-slot rotation + vmcnt(6) (full-iter cover).
__global__ __launch_bounds__(512) void attn_pc(
    const float* __restrict__ q, const float* __restrict__ rep,
    const __bf16* __restrict__ kb, const __bf16* __restrict__ vtb,
    float* __restrict__ out, float* __restrict__ attn)
{
    __shared__ __attribute__((aligned(16))) __bf16 vslot[3][8192];  // 48KB, 3-slot rotation
    __shared__ __attribute__((aligned(16))) __bf16 qs[BQ][136];     // 8.7KB
    __shared__ __attribute__((aligned(16))) __bf16 ps[2][BQ][72];   // 9.2KB
    __shared__ float redsum[2][2][2][16];                           // [gp][rg][ch]
    __shared__ float dinv_lds[BQ];

    const int tid = threadIdx.x;
    const int bid = blockIdx.x;
    const int b   = bid & 7;
    const int g   = bid >> 3;
    // balanced pairing (r8 proven): CU gets qt pair (63-g, g)
    const int qt  = (g < 32) ? (63 - g) : (g - 32);
    const int i0  = qt * BQ;
    const int NT  = ((qt * BQ + (BQ - 2)) >> 6) + 1;

    const int gp   = tid >> 8;        // pass A: kt parity; pass B: 0=producer 1=consumer
    const int gtid = tid & 255;
    const int gw   = gtid >> 6;       // wave within group 0..3
    const int lane = tid & 63;
    const int rg   = gw >> 1;
    const int ch   = gw & 1;
    const int lr   = lane & 15;
    const int lg   = lane >> 4;

    auto stageV = [&](int kt, int slot) {
        const char* src = (const char*)vtb + (((size_t)(b * 32 + kt)) << 14);
        char* dst = (char*)&vslot[slot][0];
#pragma unroll
        for (int i2 = 0; i2 < 4; ++i2) {
            const int n0 = (gw * 4 + i2) * 64;
            gload_lds16(src + (size_t)(n0 + lane) * 16, dst + (size_t)n0 * 16);
        }
    };
    auto vfrag = [&](int slot, int drow, int u) -> bfv8 {
        return *(const bfv8*)&vslot[slot][(drow * 8 + (u ^ (drow & 7))) * 8];
    };

    // ---- prologue: consumer group issues V(0) (lands during pass A) ----
    if (gp == 1) stageV(0, 0);

    // stage Q -> bf16 LDS: 512 threads, exactly one bfv8 each
    {
        const int row = tid >> 4, c8 = tid & 15;
        const float4 f0 = *(const float4*)&q[((size_t)(b * S + i0 + row)) * D + c8 * 8];
        const float4 f1 = *(const float4*)&q[((size_t)(b * S + i0 + row)) * D + c8 * 8 + 4];
        bfv8 t;
        t[0] = (__bf16)f0.x; t[1] = (__bf16)f0.y; t[2] = (__bf16)f0.z; t[3] = (__bf16)f0.w;
        t[4] = (__bf16)f1.x; t[5] = (__bf16)f1.y; t[6] = (__bf16)f1.z; t[7] = (__bf16)f1.w;
        *(bfv8*)&qs[row][c8 * 8] = t;
    }

    // per-lane column-validity bitmasks
    unsigned int vm0 = 0, vm1 = 0;
    for (int kt = 0; kt < NT; ++kt) {
        const unsigned int t0 = (rep[(size_t)b * S + kt * BK + ch * 32 + lr]      > 0.5f) ? 1u : 0u;
        const unsigned int t1 = (rep[(size_t)b * S + kt * BK + ch * 32 + 16 + lr] > 0.5f) ? 1u : 0u;
        vm0 |= t0 << kt;
        vm1 |= t1 << kt;
    }

    int  i_r[4];
    bool bi[4];
#pragma unroll
    for (int r = 0; r < 4; ++r) {
        i_r[r] = i0 + rg * 16 + lg * 4 + r;
        bi[r]  = rep[(size_t)b * S + i_r[r]] > 0.5f;
    }
    __syncthreads();   // qs ready; V(0) drained

    bfv8 qa[4];
#pragma unroll
    for (int ks = 0; ks < 4; ++ks)
        qa[ks] = *(const bfv8*)&qs[rg * 16 + lr][ks * 32 + lg * 8];

    // ---- K fragment global offsets (r7-verified) ----
    const int krow = ch * 32 + lr;
    const int csw  = krow & 7;
    int koff[4];
#pragma unroll
    for (int ks = 0; ks < 4; ++ks)
        koff[ks] = krow * 256 + (((ks * 4 + lg) ^ csw) << 4);
    const char* kbb = (const char*)kb + (((size_t)(b * 32)) << 14);

    // ============ pass A: barrier-free, groups split kt even/odd, unroll-2 ============
    float lsum[4] = {0.f, 0.f, 0.f, 0.f};
#pragma unroll 2
    for (int kt = gp; kt < NT; kt += 2) {
        const char* tp = kbb + ((size_t)kt << 14);
        bfv8 kf0[4], kf1[4];
#pragma unroll
        for (int ks = 0; ks < 4; ++ks) {
            kf0[ks] = *(const bfv8*)(tp + koff[ks]);
            kf1[ks] = *(const bfv8*)(tp + koff[ks] + 4096);
        }
        f32x4 acc0 = {0.f, 0.f, 0.f, 0.f}, acc1 = {0.f, 0.f, 0.f, 0.f};
#pragma unroll
        for (int ks = 0; ks < 4; ++ks) {
            acc0 = mfma16(qa[ks], kf0[ks], acc0);
            acc1 = mfma16(qa[ks], kf1[ks], acc1);
        }

        const int j0 = kt * BK + ch * 32 + lr;
        const int j1 = j0 + 16;
        const bool vj0 = (vm0 >> kt) & 1;
        const bool vj1 = (vm1 >> kt) & 1;
#pragma unroll
        for (int r = 0; r < 4; ++r) {
            const int i = i_r[r];
            const float p0 = (bi[r] && vj0 && (j0 < i))
                ? __expf(acc0[r] * INV_SQRT_D - (float)(i - j0)) : 0.f;
            const float p1 = (bi[r] && vj1 && (j1 < i))
                ? __expf(acc1[r] * INV_SQRT_D - (float)(i - j1)) : 0.f;
            lsum[r] += p0 + p1;
        }
    }

    // ---- reduce row sums (group axis) ----
#pragma unroll
    for (int r = 0; r < 4; ++r) {
        lsum[r] += __shfl_xor(lsum[r], 1);
        lsum[r] += __shfl_xor(lsum[r], 2);
        lsum[r] += __shfl_xor(lsum[r], 4);
        lsum[r] += __shfl_xor(lsum[r], 8);
    }
    if (lr == 0) {
#pragma unroll
        for (int r = 0; r < 4; ++r) redsum[gp][rg][ch][lg * 4 + r] = lsum[r];
    }

    // producer prefetches K(0) fragments (in flight across reduce barriers)
    bfv8 kc0[4], kc1[4];
    if (gp == 0) {
#pragma unroll
        for (int ks = 0; ks < 4; ++ks) {
            kc0[ks] = *(const bfv8*)(kbb + koff[ks]);
            kc1[ks] = *(const bfv8*)(kbb + koff[ks] + 4096);
        }
    }

    __syncthreads();
    if (tid < BQ) {
        const float s = redsum[0][tid >> 4][0][tid & 15] + redsum[0][tid >> 4][1][tid & 15]
                      + redsum[1][tid >> 4][0][tid & 15] + redsum[1][tid >> 4][1][tid & 15];
        dinv_lds[tid] = 1.f / (s + ((s == 0.f) ? 1.f : 0.f) + 1e-20f);
    }
    __syncthreads();

    float dinv[4];
#pragma unroll
    for (int r = 0; r < 4; ++r) dinv[r] = dinv_lds[rg * 16 + lg * 4 + r];

    // ============ pass B: producer/consumer pipeline, 1 barrier/iter ============
    f32x4 oacc[4];
#pragma unroll
    for (int nf = 0; nf < 4; ++nf) oacc[nf] = (f32x4){0.f, 0.f, 0.f, 0.f};

    const int arow = gtid >> 3;
    const int ac   = (gtid & 7) * 8;

    for (int kt = 0; kt < NT; ++kt) {
        if (gp == 0) {
            // ---- producer: QK(kt) from registers ----
            f32x4 acc0 = {0.f, 0.f, 0.f, 0.f}, acc1 = {0.f, 0.f, 0.f, 0.f};
#pragma unroll
            for (int ks = 0; ks < 4; ++ks) {
                acc0 = mfma16(qa[ks], kc0[ks], acc0);
                acc1 = mfma16(qa[ks], kc1[ks], acc1);
            }

            // prefetch K(kt+1) NOW (flies during exp + barrier)
            if (kt + 1 < NT) {
                const char* tp = kbb + ((size_t)(kt + 1) << 14);
#pragma unroll
                for (int ks = 0; ks < 4; ++ks) {
                    kc0[ks] = *(const bfv8*)(tp + koff[ks]);
                    kc1[ks] = *(const bfv8*)(tp + koff[ks] + 4096);
                }
            }

            const int j0 = kt * BK + ch * 32 + lr;
            const int j1 = j0 + 16;
            const bool vj0 = (vm0 >> kt) & 1;
            const bool vj1 = (vm1 >> kt) & 1;
#pragma unroll
            for (int r = 0; r < 4; ++r) {
                const int i = i_r[r];
                const float p0 = (bi[r] && vj0 && (j0 < i))
                    ? __expf(acc0[r] * INV_SQRT_D - (float)(i - j0)) * dinv[r] : 0.f;
                const float p1 = (bi[r] && vj1 && (j1 < i))
                    ? __expf(acc1[r] * INV_SQRT_D - (float)(i - j1)) * dinv[r] : 0.f;
                ps[kt & 1][rg * 16 + lg * 4 + r][ch * 32 + lr]      = (__bf16)p0;
                ps[kt & 1][rg * 16 + lg * 4 + r][ch * 32 + 16 + lr] = (__bf16)p1;
            }
            asm volatile("s_waitcnt lgkmcnt(0)" ::: "memory");   // ps writes visible
        } else {
            // ---- consumer: stage V(kt+1) (full-iter cover); PV(kt-1); attn(kt-1) ----
            if (kt + 1 < NT) stageV(kt + 1, (kt + 1) % 3);

            if (kt >= 1) {
                const int pp = (kt - 1) & 1;
                const int vs = (kt - 1) % 3;
#pragma unroll
                for (int ks = 0; ks < 2; ++ks) {
                    const bfv8 pa = *(const bfv8*)&ps[pp][rg * 16 + lr][ks * 32 + lg * 8];
#pragma unroll
                    for (int nf = 0; nf < 4; ++nf) {
                        const bfv8 vf = vfrag(vs, ch * 64 + nf * 16 + lr, ks * 4 + lg);
                        oacc[nf] = mfma16(pa, vf, oacc[nf]);
                    }
                }

                // coalesced attn tile store (newest in vmem queue, stays in flight)
                const bfv8 t = *(const bfv8*)&ps[pp][arow][ac];
                float4 f0, f1;
                f0.x = (float)t[0]; f0.y = (float)t[1]; f0.z = (float)t[2]; f0.w = (float)t[3];
                f1.x = (float)t[4]; f1.y = (float)t[5]; f1.z = (float)t[6]; f1.w = (float)t[7];
                float* ap = &attn[((size_t)(b * S + i0 + arow)) * S + (kt - 1) * BK + ac];
                *(float4*)ap = f0;
                *(float4*)(ap + 4) = f1;
            }

            // retire PREVIOUS stage (oldest 4+2); this iter's stage + stores stay in flight
            asm volatile("s_waitcnt vmcnt(6)" ::: "memory");
        }
        __builtin_amdgcn_s_barrier();
        asm volatile("" ::: "memory");
    }

    // ============ epilogue ============
    if (gp == 1) {
        // ensure V(NT-1) staging fully landed (allow last 2 attn stores in flight)
        asm volatile("s_waitcnt vmcnt(2)" ::: "memory");
        const int pp = (NT - 1) & 1;
        const int vs = (NT - 1) % 3;
#pragma unroll
        for (int ks = 0; ks < 2; ++ks) {
            const bfv8 pa = *(const bfv8*)&ps[pp][rg * 16 + lr][ks * 32 + lg * 8];
#pragma unroll
            for (int nf = 0; nf < 4; ++nf) {
                const bfv8 vf = vfrag(vs, ch * 64 + nf * 16 + lr, ks * 4 + lg);
                oacc[nf] = mfma16(pa, vf, oacc[nf]);
            }
        }
        {
            const bfv8 t = *(const bfv8*)&ps[pp][arow][ac];
            float4 f0, f1;
            f0.x = (float)t[0]; f0.y = (float)t[1]; f0.z = (float)t[2]; f0.w = (float)t[3];
            f1.x = (float)t[4]; f1.y = (float)t[5]; f1.z = (float)t[6]; f1.w = (float)t[7];
            float* ap = &attn[((size_t)(b * S + i0 + arow)) * S + (NT - 1) * BK + ac];
            *(float4*)ap = f0;
            *(float4*)(ap + 4) = f1;
        }
#pragma unroll
        for (int nf = 0; nf < 4; ++nf)
#pragma unroll
            for (int r = 0; r < 4; ++r)
                out[((size_t)(b * S + i_r[r])) * D + ch * 64 + nf * 16 + lr] = oacc[nf][r];
    } else {
        // producer group zero-fills attn tiles above the block diagonal
        const int zt = NKT - NT;
        const float4 z4 = make_float4(0.f, 0.f, 0.f, 0.f);
        for (int u = tid; u < zt * 512; u += 256) {
            const int t   = u >> 9;
            const int rem = u & 511;
            const int row = rem >> 4;
            const int c4  = rem & 15;
            *(float4*)&attn[((size_t)(b * S + i0 + row)) * S + (NT + t) * BK + c4 * 4] = z4;
        }
    }
}

// ============ fallback (proven) if ws too small ============
__global__ __launch_bounds__(256) void attn_kernel_fb(
    const float* __restrict__ q, const float* __restrict__ k,
    const float* __restrict__ v, const float* __restrict__ rep,
    float* __restrict__ out, float* __restrict__ attn)
{
    __shared__ __attribute__((aligned(16))) __bf16 qs [BQ][136];
    __shared__ __attribute__((aligned(16))) __bf16 ksm[BK][136];
    __shared__ __attribute__((aligned(16))) __bf16 vsT[D][72];
    __shared__ __attribute__((aligned(16))) __bf16 psl[BQ][72];
    __shared__ float redsum[2][2][16];
    __shared__ float dinv_lds[BQ];

    const int tid  = threadIdx.x;
    const int bid  = blockIdx.x;
    const int b    = bid & 7;
    const int qt   = (NQT - 1) - (bid >> 3);
    const int i0   = qt * BQ;
    const int NT   = ((qt * BQ + (BQ - 2)) >> 6) + 1;

    const int lane = tid & 63;
    const int w    = tid >> 6;
    const int rg   = w >> 1;
    const int ch   = w & 1;
    const int lr   = lane & 15;
    const int lg   = lane >> 4;

    for (int c = tid; c < BQ * 16; c += 256) {
        const int row = c >> 4, c8 = c & 15;
        const float4 f0 = *(const float4*)&q[((size_t)(b * S + i0 + row)) * D + c8 * 8];
        const float4 f1 = *(const float4*)&q[((size_t)(b * S + i0 + row)) * D + c8 * 8 + 4];
        bfv8 t;
        t[0] = (__bf16)f0.x; t[1] = (__bf16)f0.y; t[2] = (__bf16)f0.z; t[3] = (__bf16)f0.w;
        t[4] = (__bf16)f1.x; t[5] = (__bf16)f1.y; t[6] = (__bf16)f1.z; t[7] = (__bf16)f1.w;
        *(bfv8*)&qs[row][c8 * 8] = t;
    }
    __syncthreads();

    bfv8 qa[4];
#pragma unroll
    for (int ks = 0; ks < 4; ++ks)
        qa[ks] = *(const bfv8*)&qs[rg * 16 + lr][ks * 32 + lg * 8];

    int  i_r[4];
    bool bi[4];
#pragma unroll
    for (int r = 0; r < 4; ++r) {
        i_r[r] = i0 + rg * 16 + lg * 4 + r;
        bi[r]  = rep[(size_t)b * S + i_r[r]] > 0.5f;
    }

    float lsum[4] = {0.f, 0.f, 0.f, 0.f};
    for (int kt = 0; kt < NT; ++kt) {
        __syncthreads();
        for (int c = tid; c < BK * 16; c += 256) {
            const int row = c >> 4, c8 = c & 15;
            const float4 f0 = *(const float4*)&k[((size_t)(b * S + kt * BK + row)) * D + c8 * 8];
            const float4 f1 = *(const float4*)&k[((size_t)(b * S + kt * BK + row)) * D + c8 * 8 + 4];
            bfv8 t;
            t[0] = (__bf16)f0.x; t[1] = (__bf16)f0.y; t[2] = (__bf16)f0.z; t[3] = (__bf16)f0.w;
            t[4] = (__bf16)f1.x; t[5] = (__bf16)f1.y; t[6] = (__bf16)f1.z; t[7] = (__bf16)f1.w;
            *(bfv8*)&ksm[row][c8 * 8] = t;
        }
        __syncthreads();

        f32x4 acc0 = {0.f, 0.f, 0.f, 0.f}, acc1 = {0.f, 0.f, 0.f, 0.f};
#pragma unroll
        for (int ks = 0; ks < 4; ++ks) {
            const bfv8 b0 = *(const bfv8*)&ksm[ch * 32 + lr][ks * 32 + lg * 8];
            const bfv8 b1 = *(const bfv8*)&ksm[ch * 32 + 16 + lr][ks * 32 + lg * 8];
            acc0 = mfma16(qa[ks], b0, acc0);
            acc1 = mfma16(qa[ks], b1, acc1);
        }
        const int j0 = kt * BK + ch * 32 + lr;
        const int j1 = j0 + 16;
        const bool vj0 = rep[(size_t)b * S + j0] > 0.5f;
        const bool vj1 = rep[(size_t)b * S + j1] > 0.5f;
#pragma unroll
        for (int r = 0; r < 4; ++r) {
            const int i = i_r[r];
            const float p0 = (bi[r] && vj0 && (j0 < i))
                ? __expf(acc0[r] * INV_SQRT_D - (float)(i - j0)) : 0.f;
            const float p1 = (bi[r] && vj1 && (j1 < i))
                ? __expf(acc1[r] * INV_SQRT_D - (float)(i - j1)) : 0.f;
            lsum[r] += p0 + p1;
        }
    }

#pragma unroll
    for (int r = 0; r < 4; ++r) {
        lsum[r] += __shfl_xor(lsum[r], 1);
        lsum[r] += __shfl_xor(lsum[r], 2);
        lsum[r] += __shfl_xor(lsum[r], 4);
        lsum[r] += __shfl_xor(lsum[r], 8);
    }
    if (lr == 0) {
#pragma unroll
        for (int r = 0; r < 4; ++r) redsum[rg][ch][lg * 4 + r] = lsum[r];
    }
    __syncthreads();
    if (tid < BQ) {
        const float s = redsum[tid >> 4][0][tid & 15] + redsum[tid >> 4][1][tid & 15];
        dinv_lds[tid] = 1.f / (s + ((s == 0.f) ? 1.f : 0.f) + 1e-20f);
    }
    __syncthreads();

    float dinv[4];
#pragma unroll
    for (int r = 0; r < 4; ++r) dinv[r] = dinv_lds[rg * 16 + lg * 4 + r];

    f32x4 oacc[4];
#pragma unroll
    for (int nf = 0; nf < 4; ++nf) oacc[nf] = (f32x4){0.f, 0.f, 0.f, 0.f};

    for (int kt = 0; kt < NT; ++kt) {
        __syncthreads();
        for (int c = tid; c < BK * 16; c += 256) {
            const int row = c >> 4, c8 = c & 15;
            const float4 f0 = *(const float4*)&k[((size_t)(b * S + kt * BK + row)) * D + c8 * 8];
            const float4 f1 = *(const float4*)&k[((size_t)(b * S + kt * BK + row)) * D + c8 * 8 + 4];
            bfv8 t;
            t[0] = (__bf16)f0.x; t[1] = (__bf16)f0.y; t[2] = (__bf16)f0.z; t[3] = (__bf16)f0.w;
            t[4] = (__bf16)f1.x; t[5] = (__bf16)f1.y; t[6] = (__bf16)f1.z; t[7] = (__bf16)f1.w;
            *(bfv8*)&ksm[row][c8 * 8] = t;
        }
        for (int u = tid; u < 1024; u += 256) {
            const int p  = u & 31;
            const int dq = u >> 5;
            const float4 va = *(const float4*)&v[((size_t)(b * S + kt * BK + 2 * p)) * D + dq * 4];
            const float4 vb = *(const float4*)&v[((size_t)(b * S + kt * BK + 2 * p + 1)) * D + dq * 4];
            *(unsigned int*)&vsT[dq * 4 + 0][2 * p] = pack2(va.x, vb.x);
            *(unsigned int*)&vsT[dq * 4 + 1][2 * p] = pack2(va.y, vb.y);
            *(unsigned int*)&vsT[dq * 4 + 2][2 * p] = pack2(va.z, vb.z);
            *(unsigned int*)&vsT[dq * 4 + 3][2 * p] = pack2(va.w, vb.w);
        }
        __syncthreads();

        f32x4 acc0 = {0.f, 0.f, 0.f, 0.f}, acc1 = {0.f, 0.f, 0.f, 0.f};
#pragma unroll
        for (int ks = 0; ks < 4; ++ks) {
            const bfv8 b0 = *(const bfv8*)&ksm[ch * 32 + lr][ks * 32 + lg * 8];
            const bfv8 b1 = *(const bfv8*)&ksm[ch * 32 + 16 + lr][ks * 32 + lg * 8];
            acc0 = mfma16(qa[ks], b0, acc0);
            acc1 = mfma16(qa[ks], b1, acc1);
        }
        const int j0 = kt * BK + ch * 32 + lr;
        const int j1 = j0 + 16;
        const bool vj0 = rep[(size_t)b * S + j0] > 0.5f;
        const bool vj1 = rep[(size_t)b * S + j1] > 0.5f;
#pragma unroll
        for (int r = 0; r < 4; ++r) {
            const int i = i_r[r];
            const float p0 = (bi[r] && vj0 && (j0 < i))
                ? __expf(acc0[r] * INV_SQRT_D - (float)(i - j0)) * dinv[r] : 0.f;
            const float p1 = (bi[r] && vj1 && (j1 < i))
                ? __expf(acc1[r] * INV_SQRT_D - (float)(i - j1)) * dinv[r] : 0.f;
            attn[((size_t)(b * S + i)) * S + j0] = p0;
            attn[((size_t)(b * S + i)) * S + j1] = p1;
            psl[rg * 16 + lg * 4 + r][ch * 32 + lr]      = (__bf16)p0;
            psl[rg * 16 + lg * 4 + r][ch * 32 + 16 + lr] = (__bf16)p1;
        }
        __syncthreads();

#pragma unroll
        for (int ks = 0; ks < 2; ++ks) {
            const bfv8 pa = *(const bfv8*)&psl[rg * 16 + lr][ks * 32 + lg * 8];
#pragma unroll
            for (int nf = 0; nf < 4; ++nf) {
                const bfv8 vf = *(const bfv8*)&vsT[ch * 64 + nf * 16 + lr][ks * 32 + lg * 8];
                oacc[nf] = mfma16(pa, vf, oacc[nf]);
            }
        }
    }

#pragma unroll
    for (int nf = 0; nf < 4; ++nf)
#pragma unroll
        for (int r = 0; r < 4; ++r)
            out[((size_t)(b * S + i_r[r])) * D + ch * 64 + nf * 16 + lr] = oacc[nf][r];

    const int zt = NKT - NT;
    const float4 z4 = make_float4(0.f, 0.f, 0.f, 0.f);
    for (int u = tid; u < zt * 512; u += 256) {
        const int t   = u >> 9;
        const int rem = u & 511;
        const int row = rem >> 4;
        const int c4  = rem & 15;
        *(float4*)&attn[((size_t)(b * S + i0 + row)) * S + (NT + t) * BK + c4 * 4] = z4;
    }
}

extern "C" void kernel_launch(void* const* d_in, const int* in_sizes, int n_in,
                              void* d_out, int out_size, void* d_ws, size_t ws_size,
                              hipStream_t stream)
{
    const float* q   = (const float*)d_in[0];
    const float* k   = (const float*)d_in[1];
    const float* v   = (const float*)d_in[2];
    const float* rep = (const float*)d_in[3];
    float* out  = (float*)d_out;
    float* attn = out + (size_t)NBATCH * S * D;

    const size_t kb_elems = (size_t)NBATCH * S * D;   // bf16 elems (4MB each buf)
    const size_t need     = kb_elems * 2 * 2;         // kb + vtb bytes = 16.78 MB

    if (ws_size < need) {
        hipLaunchKernelGGL(attn_kernel_fb, dim3(NBATCH * NQT), dim3(256), 0, stream,
                           q, k, v, rep, out, attn);
        return;
    }

    __bf16* kb  = (__bf16*)d_ws;
    __bf16* vtb = kb + kb_elems;

    hipLaunchKernelGGL(prep_kernel, dim3(1280), dim3(256), 0, stream, k, v, kb, vtb);
    hipLaunchKernelGGL(attn_pc, dim3(NBATCH * NQT), dim3(512), 0, stream,
                       q, rep, kb, vtb, out, attn);
}

// Round 15
// 58.206 us; speedup vs baseline: 1.3287x; 1.0384x over previous
//
#include <hip/hip_runtime.h>

#define NBATCH 8
#define S 2048
#define D 128
#define BQ 32
#define BK 64
#define NKT 32
#define NQT 64
#define INV_SQRT_D 0.08838834764831845f

typedef __bf16 bfv8 __attribute__((ext_vector_type(8)));
typedef float f32x4 __attribute__((ext_vector_type(4)));

__device__ __forceinline__ f32x4 mfma16(bfv8 a, bfv8 b, f32x4 c) {
    return __builtin_amdgcn_mfma_f32_16x16x32_bf16(a, b, c, 0, 0, 0);
}

__device__ __forceinline__ unsigned int pack2(float lo, float hi) {
    unsigned short a = __builtin_bit_cast(unsigned short, (__bf16)lo);
    unsigned short b = __builtin_bit_cast(unsigned short, (__bf16)hi);
    return (unsigned int)a | ((unsigned int)b << 16);
}

__device__ __forceinline__ void gload_lds16(const void* g, void* l) {
    __builtin_amdgcn_global_load_lds(
        (const __attribute__((address_space(1))) unsigned int*)g,
        (__attribute__((address_space(3))) unsigned int*)l, 16, 0, 0);
}

__device__ __forceinline__ void nt_store4(float* p, f32x4 v) {
    __builtin_nontemporal_store(v, (f32x4*)p);
}

// ============ prep: K -> bf16 swizzled tiles; V -> bf16 transposed swizzled ============
__global__ __launch_bounds__(256) void prep_kernel(
    const float* __restrict__ k, const float* __restrict__ v,
    __bf16* __restrict__ kb, __bf16* __restrict__ vtb)
{
    __shared__ __bf16 lds[64][132];
    const int bidx = blockIdx.x;
    const int tid  = threadIdx.x;

    if (bidx < 1024) {                 // K part: fully coalesced
        const int t   = bidx * 256 + tid;
        const int b   = t >> 15;
        const int kt  = (t >> 10) & 31;
        const int row = (t >> 4) & 63;
        const int u   = t & 15;
        const float4 f0 = *(const float4*)&k[((size_t)(b * S + kt * 64 + row)) * D + u * 8];
        const float4 f1 = *(const float4*)&k[((size_t)(b * S + kt * 64 + row)) * D + u * 8 + 4];
        bfv8 o;
        o[0] = (__bf16)f0.x; o[1] = (__bf16)f0.y; o[2] = (__bf16)f0.z; o[3] = (__bf16)f0.w;
        o[4] = (__bf16)f1.x; o[5] = (__bf16)f1.y; o[6] = (__bf16)f1.z; o[7] = (__bf16)f1.w;
        const size_t unit = ((size_t)((b * 32 + kt) * 64 + row)) * 16 + (u ^ (row & 7));
        *(bfv8*)&kb[unit * 8] = o;
    } else {                           // V part: LDS-staged transpose
        const int vb = bidx - 1024;
        const int b  = vb >> 5;
        const int kt = vb & 31;
#pragma unroll
        for (int p = 0; p < 8; ++p) {
            const int idx = p * 256 + tid;
            const int kv  = idx >> 5;
            const int c4  = idx & 31;
            const float4 f = *(const float4*)&v[((size_t)(b * S + kt * 64 + kv)) * D + c4 * 4];
            __bf16* dst = &lds[kv][c4 * 4];
            dst[0] = (__bf16)f.x; dst[1] = (__bf16)f.y; dst[2] = (__bf16)f.z; dst[3] = (__bf16)f.w;
        }
        __syncthreads();
#pragma unroll
        for (int p = 0; p < 4; ++p) {
            const int idx = p * 256 + tid;
            const int d   = idx >> 3;
            const int u   = idx & 7;
            bfv8 o;
#pragma unroll
            for (int j = 0; j < 8; ++j) o[j] = lds[u * 8 + j][d];
            const size_t unit = ((size_t)((b * 32 + kt) * 128 + d)) * 8 + (u ^ (d & 7));
            *(bfv8*)&vtb[unit * 8] = o;
        }
    }
}

// ============ main: 512-thread producer/consumer pipeline + ragged-mask work skipping ======
__global__ __launch_bounds__(512) void attn_pc(
    const float* __restrict__ q, const float* __restrict__ rep,
    const __bf16* __restrict__ kb, const __bf16* __restrict__ vtb,
    float* __restrict__ out, float* __restrict__ attn)
{
    __shared__ __attribute__((aligned(16))) __bf16 vslot[3][8192];  // 48KB, 3-slot rotation
    __shared__ __attribute__((aligned(16))) __bf16 qs[BQ][136];
    __shared__ __attribute__((aligned(16))) __bf16 ps[2][BQ][72];
    __shared__ float redsum[2][2][2][16];
    __shared__ float dinv_lds[BQ];

    const int tid = threadIdx.x;
    const int bid = blockIdx.x;
    const int b   = bid & 7;
    const int g   = bid >> 3;
    const int qt  = (g < 32) ? (63 - g) : (g - 32);   // balanced pairing (r8 proven)
    const int i0  = qt * BQ;
    const int NT  = ((qt * BQ + (BQ - 2)) >> 6) + 1;

    const int gp   = tid >> 8;
    const int gtid = tid & 255;
    const int gw   = gtid >> 6;
    const int lane = tid & 63;
    const int rg   = gw >> 1;
    const int ch   = gw & 1;
    const int lr   = lane & 15;
    const int lg   = lane >> 4;

    // ---- ragged-mask work skipping (valid tokens are contiguous prefix of length L) ----
    // fully-invalid q-tile: i0 >= L  -> attn rows and out rows are all zero; skip compute
    if (rep[(size_t)b * S + i0] <= 0.5f) {
        const f32x4 z = {0.f, 0.f, 0.f, 0.f};
        for (int u = tid; u < BQ * (S / 4); u += 512) {
            const int row = u >> 9;          // u / 512
            const int c4  = u & 511;
            nt_store4(&attn[((size_t)(b * S + i0 + row)) * S + c4 * 4], z);
        }
        for (int u = tid; u < BQ * (D / 4); u += 512) {
            const int row = u >> 5;
            const int c4  = u & 31;
            nt_store4(&out[((size_t)(b * S + i0 + row)) * D + c4 * 4], z);
        }
        return;
    }
    // valid-col tile count NC = ceil(L/64) via lane ballot (prefix-contiguous mask)
    const bool lv = (lane < 32) && (rep[(size_t)b * S + (size_t)lane * 64] > 0.5f);
    const int NC  = __popcll(__ballot(lv));
    const int NTc = (NT < NC) ? NT : NC;

    auto stageV = [&](int kt, int slot) {
        const char* src = (const char*)vtb + (((size_t)(b * 32 + kt)) << 14);
        char* dst = (char*)&vslot[slot][0];
#pragma unroll
        for (int i2 = 0; i2 < 4; ++i2) {
            const int n0 = (gw * 4 + i2) * 64;
            gload_lds16(src + (size_t)(n0 + lane) * 16, dst + (size_t)n0 * 16);
        }
    };
    auto vfrag = [&](int slot, int drow, int u) -> bfv8 {
        return *(const bfv8*)&vslot[slot][(drow * 8 + (u ^ (drow & 7))) * 8];
    };

    // ---- prologue: consumer group issues V(0) (lands during pass A) ----
    if (gp == 1) stageV(0, 0);

    // stage Q -> bf16 LDS: 512 threads, one bfv8 each
    {
        const int row = tid >> 4, c8 = tid & 15;
        const float4 f0 = *(const float4*)&q[((size_t)(b * S + i0 + row)) * D + c8 * 8];
        const float4 f1 = *(const float4*)&q[((size_t)(b * S + i0 + row)) * D + c8 * 8 + 4];
        bfv8 t;
        t[0] = (__bf16)f0.x; t[1] = (__bf16)f0.y; t[2] = (__bf16)f0.z; t[3] = (__bf16)f0.w;
        t[4] = (__bf16)f1.x; t[5] = (__bf16)f1.y; t[6] = (__bf16)f1.z; t[7] = (__bf16)f1.w;
        *(bfv8*)&qs[row][c8 * 8] = t;
    }

    // per-lane column-validity bitmasks (only tiles < NTc matter)
    unsigned int vm0 = 0, vm1 = 0;
    for (int kt = 0; kt < NTc; ++kt) {
        const unsigned int t0 = (rep[(size_t)b * S + kt * BK + ch * 32 + lr]      > 0.5f) ? 1u : 0u;
        const unsigned int t1 = (rep[(size_t)b * S + kt * BK + ch * 32 + 16 + lr] > 0.5f) ? 1u : 0u;
        vm0 |= t0 << kt;
        vm1 |= t1 << kt;
    }

    int  i_r[4];
    bool bi[4];
#pragma unroll
    for (int r = 0; r < 4; ++r) {
        i_r[r] = i0 + rg * 16 + lg * 4 + r;
        bi[r]  = rep[(size_t)b * S + i_r[r]] > 0.5f;
    }
    __syncthreads();   // qs ready; V(0) drained

    bfv8 qa[4];
#pragma unroll
    for (int ks = 0; ks < 4; ++ks)
        qa[ks] = *(const bfv8*)&qs[rg * 16 + lr][ks * 32 + lg * 8];

    // ---- K fragment global offsets (r7-verified) ----
    const int krow = ch * 32 + lr;
    const int csw  = krow & 7;
    int koff[4];
#pragma unroll
    for (int ks = 0; ks < 4; ++ks)
        koff[ks] = krow * 256 + (((ks * 4 + lg) ^ csw) << 4);
    const char* kbb = (const char*)kb + (((size_t)(b * 32)) << 14);

    // ============ pass A: barrier-free, groups split kt even/odd ============
    float lsum[4] = {0.f, 0.f, 0.f, 0.f};
#pragma unroll 2
    for (int kt = gp; kt < NTc; kt += 2) {
        const char* tp = kbb + ((size_t)kt << 14);
        bfv8 kf0[4], kf1[4];
#pragma unroll
        for (int ks = 0; ks < 4; ++ks) {
            kf0[ks] = *(const bfv8*)(tp + koff[ks]);
            kf1[ks] = *(const bfv8*)(tp + koff[ks] + 4096);
        }
        f32x4 acc0 = {0.f, 0.f, 0.f, 0.f}, acc1 = {0.f, 0.f, 0.f, 0.f};
#pragma unroll
        for (int ks = 0; ks < 4; ++ks) {
            acc0 = mfma16(qa[ks], kf0[ks], acc0);
            acc1 = mfma16(qa[ks], kf1[ks], acc1);
        }

        const int j0 = kt * BK + ch * 32 + lr;
        const int j1 = j0 + 16;
        const bool vj0 = (vm0 >> kt) & 1;
        const bool vj1 = (vm1 >> kt) & 1;
#pragma unroll
        for (int r = 0; r < 4; ++r) {
            const int i = i_r[r];
            const float p0 = (bi[r] && vj0 && (j0 < i))
                ? __expf(acc0[r] * INV_SQRT_D - (float)(i - j0)) : 0.f;
            const float p1 = (bi[r] && vj1 && (j1 < i))
                ? __expf(acc1[r] * INV_SQRT_D - (float)(i - j1)) : 0.f;
            lsum[r] += p0 + p1;
        }
    }

    // ---- reduce row sums ----
#pragma unroll
    for (int r = 0; r < 4; ++r) {
        lsum[r] += __shfl_xor(lsum[r], 1);
        lsum[r] += __shfl_xor(lsum[r], 2);
        lsum[r] += __shfl_xor(lsum[r], 4);
        lsum[r] += __shfl_xor(lsum[r], 8);
    }
    if (lr == 0) {
#pragma unroll
        for (int r = 0; r < 4; ++r) redsum[gp][rg][ch][lg * 4 + r] = lsum[r];
    }

    // producer prefetches K(0) fragments
    bfv8 kc0[4], kc1[4];
    if (gp == 0) {
#pragma unroll
        for (int ks = 0; ks < 4; ++ks) {
            kc0[ks] = *(const bfv8*)(kbb + koff[ks]);
            kc1[ks] = *(const bfv8*)(kbb + koff[ks] + 4096);
        }
    }

    __syncthreads();
    if (tid < BQ) {
        const float s = redsum[0][tid >> 4][0][tid & 15] + redsum[0][tid >> 4][1][tid & 15]
                      + redsum[1][tid >> 4][0][tid & 15] + redsum[1][tid >> 4][1][tid & 15];
        dinv_lds[tid] = 1.f / (s + ((s == 0.f) ? 1.f : 0.f) + 1e-20f);
    }
    __syncthreads();

    float dinv[4];
#pragma unroll
    for (int r = 0; r < 4; ++r) dinv[r] = dinv_lds[rg * 16 + lg * 4 + r];

    // ============ pass B: producer/consumer pipeline, 1 barrier/iter ============
    f32x4 oacc[4];
#pragma unroll
    for (int nf = 0; nf < 4; ++nf) oacc[nf] = (f32x4){0.f, 0.f, 0.f, 0.f};

    const int arow = gtid >> 3;
    const int ac   = (gtid & 7) * 8;

    for (int kt = 0; kt < NTc; ++kt) {
        if (gp == 0) {
            // ---- producer: QK(kt) from registers ----
            f32x4 acc0 = {0.f, 0.f, 0.f, 0.f}, acc1 = {0.f, 0.f, 0.f, 0.f};
#pragma unroll
            for (int ks = 0; ks < 4; ++ks) {
                acc0 = mfma16(qa[ks], kc0[ks], acc0);
                acc1 = mfma16(qa[ks], kc1[ks], acc1);
            }

            // prefetch K(kt+1) (flies during exp + barrier)
            if (kt + 1 < NTc) {
                const char* tp = kbb + ((size_t)(kt + 1) << 14);
#pragma unroll
                for (int ks = 0; ks < 4; ++ks) {
                    kc0[ks] = *(const bfv8*)(tp + koff[ks]);
                    kc1[ks] = *(const bfv8*)(tp + koff[ks] + 4096);
                }
            }

            const int j0 = kt * BK + ch * 32 + lr;
            const int j1 = j0 + 16;
            const bool vj0 = (vm0 >> kt) & 1;
            const bool vj1 = (vm1 >> kt) & 1;
#pragma unroll
            for (int r = 0; r < 4; ++r) {
                const int i = i_r[r];
                const float p0 = (bi[r] && vj0 && (j0 < i))
                    ? __expf(acc0[r] * INV_SQRT_D - (float)(i - j0)) * dinv[r] : 0.f;
                const float p1 = (bi[r] && vj1 && (j1 < i))
                    ? __expf(acc1[r] * INV_SQRT_D - (float)(i - j1)) * dinv[r] : 0.f;
                ps[kt & 1][rg * 16 + lg * 4 + r][ch * 32 + lr]      = (__bf16)p0;
                ps[kt & 1][rg * 16 + lg * 4 + r][ch * 32 + 16 + lr] = (__bf16)p1;
            }
            asm volatile("s_waitcnt lgkmcnt(0)" ::: "memory");
        } else {
            // ---- consumer: stage V(kt+1); PV(kt-1); attn(kt-1) ----
            if (kt + 1 < NTc) stageV(kt + 1, (kt + 1) % 3);

            if (kt >= 1) {
                const int pp = (kt - 1) & 1;
                const int vs = (kt - 1) % 3;
#pragma unroll
                for (int ks = 0; ks < 2; ++ks) {
                    const bfv8 pa = *(const bfv8*)&ps[pp][rg * 16 + lr][ks * 32 + lg * 8];
#pragma unroll
                    for (int nf = 0; nf < 4; ++nf) {
                        const bfv8 vf = vfrag(vs, ch * 64 + nf * 16 + lr, ks * 4 + lg);
                        oacc[nf] = mfma16(pa, vf, oacc[nf]);
                    }
                }

                const bfv8 t = *(const bfv8*)&ps[pp][arow][ac];
                f32x4 f0, f1;
                f0[0] = (float)t[0]; f0[1] = (float)t[1]; f0[2] = (float)t[2]; f0[3] = (float)t[3];
                f1[0] = (float)t[4]; f1[1] = (float)t[5]; f1[2] = (float)t[6]; f1[3] = (float)t[7];
                float* ap = &attn[((size_t)(b * S + i0 + arow)) * S + (kt - 1) * BK + ac];
                nt_store4(ap, f0);
                nt_store4(ap + 4, f1);
            }

            asm volatile("s_waitcnt vmcnt(6)" ::: "memory");
        }
        __builtin_amdgcn_s_barrier();
        asm volatile("" ::: "memory");
    }

    // ============ epilogue ============
    if (gp == 1) {
        asm volatile("s_waitcnt vmcnt(2)" ::: "memory");
        const int pp = (NTc - 1) & 1;
        const int vs = (NTc - 1) % 3;
#pragma unroll
        for (int ks = 0; ks < 2; ++ks) {
            const bfv8 pa = *(const bfv8*)&ps[pp][rg * 16 + lr][ks * 32 + lg * 8];
#pragma unroll
            for (int nf = 0; nf < 4; ++nf) {
                const bfv8 vf = vfrag(vs, ch * 64 + nf * 16 + lr, ks * 4 + lg);
                oacc[nf] = mfma16(pa, vf, oacc[nf]);
            }
        }
        {
            const bfv8 t = *(const bfv8*)&ps[pp][arow][ac];
            f32x4 f0, f1;
            f0[0] = (float)t[0]; f0[1] = (float)t[1]; f0[2] = (float)t[2]; f0[3] = (float)t[3];
            f1[0] = (float)t[4]; f1[1] = (float)t[5]; f1[2] = (float)t[6]; f1[3] = (float)t[7];
            float* ap = &attn[((size_t)(b * S + i0 + arow)) * S + (NTc - 1) * BK + ac];
            nt_store4(ap, f0);
            nt_store4(ap + 4, f1);
        }
#pragma unroll
        for (int nf = 0; nf < 4; ++nf)
#pragma unroll
            for (int r = 0; r < 4; ++r)
                out[((size_t)(b * S + i_r[r])) * D + ch * 64 + nf * 16 + lr] = oacc[nf][r];
    } else {
        // zero-fill attn tiles in [NTc, NKT): clamped-invalid cols + above-diagonal
        const int zt = NKT - NTc;
        const f32x4 z = {0.f, 0.f, 0.f, 0.f};
        for (int u = tid; u < zt * 512; u += 256) {
            const int t   = u >> 9;
            const int rem = u & 511;
            const int row = rem >> 4;
            const int c4  = rem & 15;
            nt_store4(&attn[((size_t)(b * S + i0 + row)) * S + (NTc + t) * BK + c4 * 4], z);
        }
    }
}

// ============ fallback (proven) if ws too small ============
__global__ __launch_bounds__(256) void attn_kernel_fb(
    const float* __restrict__ q, const float* __restrict__ k,
    const float* __restrict__ v, const float* __restrict__ rep,
    float* __restrict__ out, float* __restrict__ attn)
{
    __shared__ __attribute__((aligned(16))) __bf16 qs [BQ][136];
    __shared__ __attribute__((aligned(16))) __bf16 ksm[BK][136];
    __shared__ __attribute__((aligned(16))) __bf16 vsT[D][72];
    __shared__ __attribute__((aligned(16))) __bf16 psl[BQ][72];
    __shared__ float redsum[2][2][16];
    __shared__ float dinv_lds[BQ];

    const int tid  = threadIdx.x;
    const int bid  = blockIdx.x;
    const int b    = bid & 7;
    const int qt   = (NQT - 1) - (bid >> 3);
    const int i0   = qt * BQ;
    const int NT   = ((qt * BQ + (BQ - 2)) >> 6) + 1;

    const int lane = tid & 63;
    const int w    = tid >> 6;
    const int rg   = w >> 1;
    const int ch   = w & 1;
    const int lr   = lane & 15;
    const int lg   = lane >> 4;

    for (int c = tid; c < BQ * 16; c += 256) {
        const int row = c >> 4, c8 = c & 15;
        const float4 f0 = *(const float4*)&q[((size_t)(b * S + i0 + row)) * D + c8 * 8];
        const float4 f1 = *(const float4*)&q[((size_t)(b * S + i0 + row)) * D + c8 * 8 + 4];
        bfv8 t;
        t[0] = (__bf16)f0.x; t[1] = (__bf16)f0.y; t[2] = (__bf16)f0.z; t[3] = (__bf16)f0.w;
        t[4] = (__bf16)f1.x; t[5] = (__bf16)f1.y; t[6] = (__bf16)f1.z; t[7] = (__bf16)f1.w;
        *(bfv8*)&qs[row][c8 * 8] = t;
    }
    __syncthreads();

    bfv8 qa[4];
#pragma unroll
    for (int ks = 0; ks < 4; ++ks)
        qa[ks] = *(const bfv8*)&qs[rg * 16 + lr][ks * 32 + lg * 8];

    int  i_r[4];
    bool bi[4];
#pragma unroll
    for (int r = 0; r < 4; ++r) {
        i_r[r] = i0 + rg * 16 + lg * 4 + r;
        bi[r]  = rep[(size_t)b * S + i_r[r]] > 0.5f;
    }

    float lsum[4] = {0.f, 0.f, 0.f, 0.f};
    for (int kt = 0; kt < NT; ++kt) {
        __syncthreads();
        for (int c = tid; c < BK * 16; c += 256) {
            const int row = c >> 4, c8 = c & 15;
            const float4 f0 = *(const float4*)&k[((size_t)(b * S + kt * BK + row)) * D + c8 * 8];
            const float4 f1 = *(const float4*)&k[((size_t)(b * S + kt * BK + row)) * D + c8 * 8 + 4];
            bfv8 t;
            t[0] = (__bf16)f0.x; t[1] = (__bf16)f0.y; t[2] = (__bf16)f0.z; t[3] = (__bf16)f0.w;
            t[4] = (__bf16)f1.x; t[5] = (__bf16)f1.y; t[6] = (__bf16)f1.z; t[7] = (__bf16)f1.w;
            *(bfv8*)&ksm[row][c8 * 8] = t;
        }
        __syncthreads();

        f32x4 acc0 = {0.f, 0.f, 0.f, 0.f}, acc1 = {0.f, 0.f, 0.f, 0.f};
#pragma unroll
        for (int ks = 0; ks < 4; ++ks) {
            const bfv8 b0 = *(const bfv8*)&ksm[ch * 32 + lr][ks * 32 + lg * 8];
            const bfv8 b1 = *(const bfv8*)&ksm[ch * 32 + 16 + lr][ks * 32 + lg * 8];
            acc0 = mfma16(qa[ks], b0, acc0);
            acc1 = mfma16(qa[ks], b1, acc1);
        }
        const int j0 = kt * BK + ch * 32 + lr;
        const int j1 = j0 + 16;
        const bool vj0 = rep[(size_t)b * S + j0] > 0.5f;
        const bool vj1 = rep[(size_t)b * S + j1] > 0.5f;
#pragma unroll
        for (int r = 0; r < 4; ++r) {
            const int i = i_r[r];
            const float p0 = (bi[r] && vj0 && (j0 < i))
                ? __expf(acc0[r] * INV_SQRT_D - (float)(i - j0)) : 0.f;
            const float p1 = (bi[r] && vj1 && (j1 < i))
                ? __expf(acc1[r] * INV_SQRT_D - (float)(i - j1)) : 0.f;
            lsum[r] += p0 + p1;
        }
    }

#pragma unroll
    for (int r = 0; r < 4; ++r) {
        lsum[r] += __shfl_xor(lsum[r], 1);
        lsum[r] += __shfl_xor(lsum[r], 2);
        lsum[r] += __shfl_xor(lsum[r], 4);
        lsum[r] += __shfl_xor(lsum[r], 8);
    }
    if (lr == 0) {
#pragma unroll
        for (int r = 0; r < 4; ++r) redsum[rg][ch][lg * 4 + r] = lsum[r];
    }
    __syncthreads();
    if (tid < BQ) {
        const float s = redsum[tid >> 4][0][tid & 15] + redsum[tid >> 4][1][tid & 15];
        dinv_lds[tid] = 1.f / (s + ((s == 0.f) ? 1.f : 0.f) + 1e-20f);
    }
    __syncthreads();

    float dinv[4];
#pragma unroll
    for (int r = 0; r < 4; ++r) dinv[r] = dinv_lds[rg * 16 + lg * 4 + r];

    f32x4 oacc[4];
#pragma unroll
    for (int nf = 0; nf < 4; ++nf) oacc[nf] = (f32x4){0.f, 0.f, 0.f, 0.f};

    for (int kt = 0; kt < NT; ++kt) {
        __syncthreads();
        for (int c = tid; c < BK * 16; c += 256) {
            const int row = c >> 4, c8 = c & 15;
            const float4 f0 = *(const float4*)&k[((size_t)(b * S + kt * BK + row)) * D + c8 * 8];
            const float4 f1 = *(const float4*)&k[((size_t)(b * S + kt * BK + row)) * D + c8 * 8 + 4];
            bfv8 t;
            t[0] = (__bf16)f0.x; t[1] = (__bf16)f0.y; t[2] = (__bf16)f0.z; t[3] = (__bf16)f0.w;
            t[4] = (__bf16)f1.x; t[5] = (__bf16)f1.y; t[6] = (__bf16)f1.z; t[7] = (__bf16)f1.w;
            *(bfv8*)&ksm[row][c8 * 8] = t;
        }
        for (int u = tid; u < 1024; u += 256) {
            const int p  = u & 31;
            const int dq = u >> 5;
            const float4 va = *(const float4*)&v[((size_t)(b * S + kt * BK + 2 * p)) * D + dq * 4];
            const float4 vb = *(const float4*)&v[((size_t)(b * S + kt * BK + 2 * p + 1)) * D + dq * 4];
            *(unsigned int*)&vsT[dq * 4 + 0][2 * p] = pack2(va.x, vb.x);
            *(unsigned int*)&vsT[dq * 4 + 1][2 * p] = pack2(va.y, vb.y);
            *(unsigned int*)&vsT[dq * 4 + 2][2 * p] = pack2(va.z, vb.z);
            *(unsigned int*)&vsT[dq * 4 + 3][2 * p] = pack2(va.w, vb.w);
        }
        __syncthreads();

        f32x4 acc0 = {0.f, 0.f, 0.f, 0.f}, acc1 = {0.f, 0.f, 0.f, 0.f};
#pragma unroll
        for (int ks = 0; ks < 4; ++ks) {
            const bfv8 b0 = *(const bfv8*)&ksm[ch * 32 + lr][ks * 32 + lg * 8];
            const bfv8 b1 = *(const bfv8*)&ksm[ch * 32 + 16 + lr][ks * 32 + lg * 8];
            acc0 = mfma16(qa[ks], b0, acc0);
            acc1 = mfma16(qa[ks], b1, acc1);
        }
        const int j0 = kt * BK + ch * 32 + lr;
        const int j1 = j0 + 16;
        const bool vj0 = rep[(size_t)b * S + j0] > 0.5f;
        const bool vj1 = rep[(size_t)b * S + j1] > 0.5f;
#pragma unroll
        for (int r = 0; r < 4; ++r) {
            const int i = i_r[r];
            const float p0 = (bi[r] && vj0 && (j0 < i))
                ? __expf(acc0[r] * INV_SQRT_D - (float)(i - j0)) * dinv[r] : 0.f;
            const float p1 = (bi[r] && vj1 && (j1 < i))
                ? __expf(acc1[r] * INV_SQRT_D - (float)(i - j1)) * dinv[r] : 0.f;
            attn[((size_t)(b * S + i)) * S + j0] = p0;
            attn[((size_t)(b * S + i)) * S + j1] = p1;
            psl[rg * 16 + lg * 4 + r][ch * 32 + lr]      = (__bf16)p0;
            psl[rg * 16 + lg * 4 + r][ch * 32 + 16 + lr] = (__bf16)p1;
        }
        __syncthreads();

#pragma unroll
        for (int ks = 0; ks < 2; ++ks) {
            const bfv8 pa = *(const bfv8*)&psl[rg * 16 + lr][ks * 32 + lg * 8];
#pragma unroll
            for (int nf = 0; nf < 4; ++nf) {
                const bfv8 vf = *(const bfv8*)&vsT[ch * 64 + nf * 16 + lr][ks * 32 + lg * 8];
                oacc[nf] = mfma16(pa, vf, oacc[nf]);
            }
        }
    }

#pragma unroll
    for (int nf = 0; nf < 4; ++nf)
#pragma unroll
        for (int r = 0; r < 4; ++r)
            out[((size_t)(b * S + i_r[r])) * D + ch * 64 + nf * 16 + lr] = oacc[nf][r];

    const int zt = NKT - NT;
    const float4 z4 = make_float4(0.f, 0.f, 0.f, 0.f);
    for (int u = tid; u < zt * 512; u += 256) {
        const int t   = u >> 9;
        const int rem = u & 511;
        const int row = rem >> 4;
        const int c4  = rem & 15;
        *(float4*)&attn[((size_t)(b * S + i0 + row)) * S + (NT + t) * BK + c4 * 4] = z4;
    }
}

extern "C" void kernel_launch(void* const* d_in, const int* in_sizes, int n_in,
                              void* d_out, int out_size, void* d_ws, size_t ws_size,
                              hipStream_t stream)
{
    const float* q   = (const float*)d_in[0];
    const float* k   = (const float*)d_in[1];
    const float* v   = (const float*)d_in[2];
    const float* rep = (const float*)d_in[3];
    float* out  = (float*)d_out;
    float* attn = out + (size_t)NBATCH * S * D;

    const size_t kb_elems = (size_t)NBATCH * S * D;
    const size_t need     = kb_elems * 2 * 2;

    if (ws_size < need) {
        hipLaunchKernelGGL(attn_kernel_fb, dim3(NBATCH * NQT), dim3(256), 0, stream,
                           q, k, v, rep, out, attn);
        return;
    }

    __bf16* kb  = (__bf16*)d_ws;
    __bf16* vtb = kb + kb_elems;

    hipLaunchKernelGGL(prep_kernel, dim3(1280), dim3(256), 0, stream, k, v, kb, vtb);
    hipLaunchKernelGGL(attn_pc, dim3(NBATCH * NQT), dim3(512), 0, stream,
                       q, rep, kb, vtb, out, attn);
}

// Round 16
// 55.377 us; speedup vs baseline: 1.3965x; 1.0511x over previous
//
#include <hip/hip_runtime.h>

#define NBATCH 8
#define S 2048
#define D 128
#define BQ 32
#define BK 64
#define NKT 32
#define NQT 64
#define INV_SQRT_D 0.08838834764831845f

typedef __bf16 bfv8 __attribute__((ext_vector_type(8)));
typedef __bf16 bfv4 __attribute__((ext_vector_type(4)));
typedef float f32x4 __attribute__((ext_vector_type(4)));

__device__ __forceinline__ f32x4 mfma16(bfv8 a, bfv8 b, f32x4 c) {
    return __builtin_amdgcn_mfma_f32_16x16x32_bf16(a, b, c, 0, 0, 0);
}

__device__ __forceinline__ unsigned int pack2(float lo, float hi) {
    unsigned short a = __builtin_bit_cast(unsigned short, (__bf16)lo);
    unsigned short b = __builtin_bit_cast(unsigned short, (__bf16)hi);
    return (unsigned int)a | ((unsigned int)b << 16);
}

__device__ __forceinline__ void gload_lds16(const void* g, void* l) {
    __builtin_amdgcn_global_load_lds(
        (const __attribute__((address_space(1))) unsigned int*)g,
        (__attribute__((address_space(3))) unsigned int*)l, 16, 0, 0);
}

__device__ __forceinline__ void nt_store4(float* p, f32x4 v) {
    __builtin_nontemporal_store(v, (f32x4*)p);
}

// ============ prep: K -> bf16 swizzled tiles; V -> bf16 transposed swizzled ============
__global__ __launch_bounds__(256) void prep_kernel(
    const float* __restrict__ k, const float* __restrict__ v,
    __bf16* __restrict__ kb, __bf16* __restrict__ vtb)
{
    __shared__ __bf16 lds[64][132];
    const int bidx = blockIdx.x;
    const int tid  = threadIdx.x;

    if (bidx < 1024) {                 // K part: fully coalesced
        const int t   = bidx * 256 + tid;
        const int b   = t >> 15;
        const int kt  = (t >> 10) & 31;
        const int row = (t >> 4) & 63;
        const int u   = t & 15;
        const float4 f0 = *(const float4*)&k[((size_t)(b * S + kt * 64 + row)) * D + u * 8];
        const float4 f1 = *(const float4*)&k[((size_t)(b * S + kt * 64 + row)) * D + u * 8 + 4];
        bfv8 o;
        o[0] = (__bf16)f0.x; o[1] = (__bf16)f0.y; o[2] = (__bf16)f0.z; o[3] = (__bf16)f0.w;
        o[4] = (__bf16)f1.x; o[5] = (__bf16)f1.y; o[6] = (__bf16)f1.z; o[7] = (__bf16)f1.w;
        const size_t unit = ((size_t)((b * 32 + kt) * 64 + row)) * 16 + (u ^ (row & 7));
        *(bfv8*)&kb[unit * 8] = o;
    } else {                           // V part: LDS-staged transpose
        const int vb = bidx - 1024;
        const int b  = vb >> 5;
        const int kt = vb & 31;
#pragma unroll
        for (int p = 0; p < 8; ++p) {
            const int idx = p * 256 + tid;
            const int kv  = idx >> 5;
            const int c4  = idx & 31;
            const float4 f = *(const float4*)&v[((size_t)(b * S + kt * 64 + kv)) * D + c4 * 4];
            __bf16* dst = &lds[kv][c4 * 4];
            dst[0] = (__bf16)f.x; dst[1] = (__bf16)f.y; dst[2] = (__bf16)f.z; dst[3] = (__bf16)f.w;
        }
        __syncthreads();
#pragma unroll
        for (int p = 0; p < 4; ++p) {
            const int idx = p * 256 + tid;
            const int d   = idx >> 3;
            const int u   = idx & 7;
            bfv8 o;
#pragma unroll
            for (int j = 0; j < 8; ++j) o[j] = lds[u * 8 + j][d];
            const size_t unit = ((size_t)((b * 32 + kt) * 128 + d)) * 8 + (u ^ (d & 7));
            *(bfv8*)&vtb[unit * 8] = o;
        }
    }
}

// ============ main: producer/consumer pipeline + swapped QK^T (D[k][q], q lane-fixed) =====
__global__ __launch_bounds__(512) void attn_pc(
    const float* __restrict__ q, const float* __restrict__ rep,
    const __bf16* __restrict__ kb, const __bf16* __restrict__ vtb,
    float* __restrict__ out, float* __restrict__ attn)
{
    __shared__ __attribute__((aligned(16))) __bf16 vslot[3][8192];
    __shared__ __attribute__((aligned(16))) __bf16 qs[BQ][136];
    __shared__ __attribute__((aligned(16))) __bf16 ps[2][BQ][72];
    __shared__ float redsum[2][2][2][16];
    __shared__ float dinv_lds[BQ];

    const int tid = threadIdx.x;
    const int bid = blockIdx.x;
    const int b   = bid & 7;
    const int g   = bid >> 3;
    const int qt  = (g < 32) ? (63 - g) : (g - 32);   // balanced pairing (r8)
    const int i0  = qt * BQ;
    const int NT  = ((qt * BQ + (BQ - 2)) >> 6) + 1;

    const int gp   = tid >> 8;
    const int gtid = tid & 255;
    const int gw   = gtid >> 6;
    const int lane = tid & 63;
    const int rg   = gw >> 1;
    const int ch   = gw & 1;
    const int lr   = lane & 15;
    const int lg   = lane >> 4;

    // ---- ragged skip: fully-invalid q-tile ----
    if (rep[(size_t)b * S + i0] <= 0.5f) {
        const f32x4 z = {0.f, 0.f, 0.f, 0.f};
        for (int u = tid; u < BQ * (S / 4); u += 512) {
            const int row = u >> 9;
            const int c4  = u & 511;
            nt_store4(&attn[((size_t)(b * S + i0 + row)) * S + c4 * 4], z);
        }
        for (int u = tid; u < BQ * (D / 4); u += 512) {
            const int row = u >> 5;
            const int c4  = u & 31;
            nt_store4(&out[((size_t)(b * S + i0 + row)) * D + c4 * 4], z);
        }
        return;
    }
    // exact valid length L (prefix-contiguous): tile count then in-tile refine
    const bool tv = (lane < 32) && (rep[(size_t)b * S + (size_t)lane * 64] > 0.5f);
    const int NC  = __popcll(__ballot(tv));
    const int NTc = (NT < NC) ? NT : NC;
    const bool ev = rep[(size_t)b * S + (size_t)(NC - 1) * 64 + lane] > 0.5f;
    const int L   = (NC - 1) * 64 + __popcll(__ballot(ev));

    auto stageV = [&](int kt, int slot) {
        const char* src = (const char*)vtb + (((size_t)(b * 32 + kt)) << 14);
        char* dst = (char*)&vslot[slot][0];
#pragma unroll
        for (int i2 = 0; i2 < 4; ++i2) {
            const int n0 = (gw * 4 + i2) * 64;
            gload_lds16(src + (size_t)(n0 + lane) * 16, dst + (size_t)n0 * 16);
        }
    };
    auto vfrag = [&](int slot, int drow, int u) -> bfv8 {
        return *(const bfv8*)&vslot[slot][(drow * 8 + (u ^ (drow & 7))) * 8];
    };

    if (gp == 1) stageV(0, 0);

    // stage Q -> bf16 LDS
    {
        const int row = tid >> 4, c8 = tid & 15;
        const float4 f0 = *(const float4*)&q[((size_t)(b * S + i0 + row)) * D + c8 * 8];
        const float4 f1 = *(const float4*)&q[((size_t)(b * S + i0 + row)) * D + c8 * 8 + 4];
        bfv8 t;
        t[0] = (__bf16)f0.x; t[1] = (__bf16)f0.y; t[2] = (__bf16)f0.z; t[3] = (__bf16)f0.w;
        t[4] = (__bf16)f1.x; t[5] = (__bf16)f1.y; t[6] = (__bf16)f1.z; t[7] = (__bf16)f1.w;
        *(bfv8*)&qs[row][c8 * 8] = t;
    }

    // consumer needs per-r q rows for the out write
    int i_r[4];
#pragma unroll
    for (int r = 0; r < 4; ++r) i_r[r] = i0 + rg * 16 + lg * 4 + r;

    // swapped-QK per-lane constants: q row fixed per lane
    const int i_q  = i0 + rg * 16 + lr;
    const int klim = (i_q < L) ? i_q : 0;   // j<i && j<L && i<L  <=>  j<klim

    __syncthreads();   // qs ready; V(0) drained

    bfv8 qa[4];
#pragma unroll
    for (int ks = 0; ks < 4; ++ks)
        qa[ks] = *(const bfv8*)&qs[rg * 16 + lr][ks * 32 + lg * 8];

    const int krow = ch * 32 + lr;
    const int csw  = krow & 7;
    int koff[4];
#pragma unroll
    for (int ks = 0; ks < 4; ++ks)
        koff[ks] = krow * 256 + (((ks * 4 + lg) ^ csw) << 4);
    const char* kbb = (const char*)kb + (((size_t)(b * 32)) << 14);

    // ============ pass A: barrier-free, swapped QK (groups split kt parity) ============
    float lsum = 0.f;
#pragma unroll 2
    for (int kt = gp; kt < NTc; kt += 2) {
        const char* tp = kbb + ((size_t)kt << 14);
        bfv8 kf0[4], kf1[4];
#pragma unroll
        for (int ks = 0; ks < 4; ++ks) {
            kf0[ks] = *(const bfv8*)(tp + koff[ks]);
            kf1[ks] = *(const bfv8*)(tp + koff[ks] + 4096);
        }
        f32x4 acc0 = {0.f, 0.f, 0.f, 0.f}, acc1 = {0.f, 0.f, 0.f, 0.f};
#pragma unroll
        for (int ks = 0; ks < 4; ++ks) {
            acc0 = mfma16(kf0[ks], qa[ks], acc0);   // swapped: D[k][q]
            acc1 = mfma16(kf1[ks], qa[ks], acc1);
        }
        const int kbase = kt * BK + ch * 32 + lg * 4;
#pragma unroll
        for (int r = 0; r < 4; ++r) {
            const int k0 = kbase + r;
            const int k1 = kbase + 16 + r;
            const float p0 = (k0 < klim)
                ? __expf(acc0[r] * INV_SQRT_D - (float)(i_q - k0)) : 0.f;
            const float p1 = (k1 < klim)
                ? __expf(acc1[r] * INV_SQRT_D - (float)(i_q - k1)) : 0.f;
            lsum += p0 + p1;
        }
    }

    // ---- reduce: sum over lg groups (k-slots), then store per (gp,rg,ch) ----
    lsum += __shfl_xor(lsum, 16);
    lsum += __shfl_xor(lsum, 32);
    if (lane < 16) redsum[gp][rg][ch][lane] = lsum;

    // producer prefetches K(0) fragments across reduce barriers
    bfv8 kc0[4], kc1[4];
    if (gp == 0) {
#pragma unroll
        for (int ks = 0; ks < 4; ++ks) {
            kc0[ks] = *(const bfv8*)(kbb + koff[ks]);
            kc1[ks] = *(const bfv8*)(kbb + koff[ks] + 4096);
        }
    }

    __syncthreads();
    if (tid < BQ) {
        const float s = redsum[0][tid >> 4][0][tid & 15] + redsum[0][tid >> 4][1][tid & 15]
                      + redsum[1][tid >> 4][0][tid & 15] + redsum[1][tid >> 4][1][tid & 15];
        dinv_lds[tid] = 1.f / (s + ((s == 0.f) ? 1.f : 0.f) + 1e-20f);
    }
    __syncthreads();

    const float dinv = dinv_lds[rg * 16 + lr];   // producer's per-lane scalar

    // ============ pass B: producer/consumer pipeline, 1 barrier/iter ============
    f32x4 oacc[4];
#pragma unroll
    for (int nf = 0; nf < 4; ++nf) oacc[nf] = (f32x4){0.f, 0.f, 0.f, 0.f};

    const int arow = gtid >> 3;
    const int ac   = (gtid & 7) * 8;

    for (int kt = 0; kt < NTc; ++kt) {
        if (gp == 0) {
            // ---- producer: swapped QK(kt) from registers ----
            f32x4 acc0 = {0.f, 0.f, 0.f, 0.f}, acc1 = {0.f, 0.f, 0.f, 0.f};
#pragma unroll
            for (int ks = 0; ks < 4; ++ks) {
                acc0 = mfma16(kc0[ks], qa[ks], acc0);
                acc1 = mfma16(kc1[ks], qa[ks], acc1);
            }

            // prefetch K(kt+1) (flies during exp + barrier)
            if (kt + 1 < NTc) {
                const char* tp = kbb + ((size_t)(kt + 1) << 14);
#pragma unroll
                for (int ks = 0; ks < 4; ++ks) {
                    kc0[ks] = *(const bfv8*)(tp + koff[ks]);
                    kc1[ks] = *(const bfv8*)(tp + koff[ks] + 4096);
                }
            }

            const int kbase = kt * BK + ch * 32 + lg * 4;
            bfv4 w0, w1;
#pragma unroll
            for (int r = 0; r < 4; ++r) {
                const int k0 = kbase + r;
                const int k1 = kbase + 16 + r;
                const float p0 = (k0 < klim)
                    ? __expf(acc0[r] * INV_SQRT_D - (float)(i_q - k0)) * dinv : 0.f;
                const float p1 = (k1 < klim)
                    ? __expf(acc1[r] * INV_SQRT_D - (float)(i_q - k1)) * dinv : 0.f;
                w0[r] = (__bf16)p0;
                w1[r] = (__bf16)p1;
            }
            // packed 8B LDS writes: 4 consecutive kv for this lane's q row
            *(bfv4*)&ps[kt & 1][rg * 16 + lr][ch * 32 + lg * 4]      = w0;
            *(bfv4*)&ps[kt & 1][rg * 16 + lr][ch * 32 + 16 + lg * 4] = w1;

            asm volatile("s_waitcnt lgkmcnt(0)" ::: "memory");
        } else {
            // ---- consumer: stage V(kt+1); PV(kt-1); attn(kt-1) (r15-proven) ----
            if (kt + 1 < NTc) stageV(kt + 1, (kt + 1) % 3);

            if (kt >= 1) {
                const int pp = (kt - 1) & 1;
                const int vs = (kt - 1) % 3;
#pragma unroll
                for (int ks = 0; ks < 2; ++ks) {
                    const bfv8 pa = *(const bfv8*)&ps[pp][rg * 16 + lr][ks * 32 + lg * 8];
#pragma unroll
                    for (int nf = 0; nf < 4; ++nf) {
                        const bfv8 vf = vfrag(vs, ch * 64 + nf * 16 + lr, ks * 4 + lg);
                        oacc[nf] = mfma16(pa, vf, oacc[nf]);
                    }
                }

                const bfv8 t = *(const bfv8*)&ps[pp][arow][ac];
                f32x4 f0, f1;
                f0[0] = (float)t[0]; f0[1] = (float)t[1]; f0[2] = (float)t[2]; f0[3] = (float)t[3];
                f1[0] = (float)t[4]; f1[1] = (float)t[5]; f1[2] = (float)t[6]; f1[3] = (float)t[7];
                float* ap = &attn[((size_t)(b * S + i0 + arow)) * S + (kt - 1) * BK + ac];
                nt_store4(ap, f0);
                nt_store4(ap + 4, f1);
            }

            asm volatile("s_waitcnt vmcnt(6)" ::: "memory");
        }
        __builtin_amdgcn_s_barrier();
        asm volatile("" ::: "memory");
    }

    // ============ epilogue ============
    if (gp == 1) {
        asm volatile("s_waitcnt vmcnt(2)" ::: "memory");
        const int pp = (NTc - 1) & 1;
        const int vs = (NTc - 1) % 3;
#pragma unroll
        for (int ks = 0; ks < 2; ++ks) {
            const bfv8 pa = *(const bfv8*)&ps[pp][rg * 16 + lr][ks * 32 + lg * 8];
#pragma unroll
            for (int nf = 0; nf < 4; ++nf) {
                const bfv8 vf = vfrag(vs, ch * 64 + nf * 16 + lr, ks * 4 + lg);
                oacc[nf] = mfma16(pa, vf, oacc[nf]);
            }
        }
        {
            const bfv8 t = *(const bfv8*)&ps[pp][arow][ac];
            f32x4 f0, f1;
            f0[0] = (float)t[0]; f0[1] = (float)t[1]; f0[2] = (float)t[2]; f0[3] = (float)t[3];
            f1[0] = (float)t[4]; f1[1] = (float)t[5]; f1[2] = (float)t[6]; f1[3] = (float)t[7];
            float* ap = &attn[((size_t)(b * S + i0 + arow)) * S + (NTc - 1) * BK + ac];
            nt_store4(ap, f0);
            nt_store4(ap + 4, f1);
        }
#pragma unroll
        for (int nf = 0; nf < 4; ++nf)
#pragma unroll
            for (int r = 0; r < 4; ++r)
                out[((size_t)(b * S + i_r[r])) * D + ch * 64 + nf * 16 + lr] = oacc[nf][r];
    } else {
        const int zt = NKT - NTc;
        const f32x4 z = {0.f, 0.f, 0.f, 0.f};
        for (int u = tid; u < zt * 512; u += 256) {
            const int t   = u >> 9;
            const int rem = u & 511;
            const int row = rem >> 4;
            const int c4  = rem & 15;
            nt_store4(&attn[((size_t)(b * S + i0 + row)) * S + (NTc + t) * BK + c4 * 4], z);
        }
    }
}

// ============ fallback (proven) if ws too small ============
__global__ __launch_bounds__(256) void attn_kernel_fb(
    const float* __restrict__ q, const float* __restrict__ k,
    const float* __restrict__ v, const float* __restrict__ rep,
    float* __restrict__ out, float* __restrict__ attn)
{
    __shared__ __attribute__((aligned(16))) __bf16 qs [BQ][136];
    __shared__ __attribute__((aligned(16))) __bf16 ksm[BK][136];
    __shared__ __attribute__((aligned(16))) __bf16 vsT[D][72];
    __shared__ __attribute__((aligned(16))) __bf16 psl[BQ][72];
    __shared__ float redsum[2][2][16];
    __shared__ float dinv_lds[BQ];

    const int tid  = threadIdx.x;
    const int bid  = blockIdx.x;
    const int b    = bid & 7;
    const int qt   = (NQT - 1) - (bid >> 3);
    const int i0   = qt * BQ;
    const int NT   = ((qt * BQ + (BQ - 2)) >> 6) + 1;

    const int lane = tid & 63;
    const int w    = tid >> 6;
    const int rg   = w >> 1;
    const int ch   = w & 1;
    const int lr   = lane & 15;
    const int lg   = lane >> 4;

    for (int c = tid; c < BQ * 16; c += 256) {
        const int row = c >> 4, c8 = c & 15;
        const float4 f0 = *(const float4*)&q[((size_t)(b * S + i0 + row)) * D + c8 * 8];
        const float4 f1 = *(const float4*)&q[((size_t)(b * S + i0 + row)) * D + c8 * 8 + 4];
        bfv8 t;
        t[0] = (__bf16)f0.x; t[1] = (__bf16)f0.y; t[2] = (__bf16)f0.z; t[3] = (__bf16)f0.w;
        t[4] = (__bf16)f1.x; t[5] = (__bf16)f1.y; t[6] = (__bf16)f1.z; t[7] = (__bf16)f1.w;
        *(bfv8*)&qs[row][c8 * 8] = t;
    }
    __syncthreads();

    bfv8 qa[4];
#pragma unroll
    for (int ks = 0; ks < 4; ++ks)
        qa[ks] = *(const bfv8*)&qs[rg * 16 + lr][ks * 32 + lg * 8];

    int  i_r[4];
    bool bi[4];
#pragma unroll
    for (int r = 0; r < 4; ++r) {
        i_r[r] = i0 + rg * 16 + lg * 4 + r;
        bi[r]  = rep[(size_t)b * S + i_r[r]] > 0.5f;
    }

    float lsum[4] = {0.f, 0.f, 0.f, 0.f};
    for (int kt = 0; kt < NT; ++kt) {
        __syncthreads();
        for (int c = tid; c < BK * 16; c += 256) {
            const int row = c >> 4, c8 = c & 15;
            const float4 f0 = *(const float4*)&k[((size_t)(b * S + kt * BK + row)) * D + c8 * 8];
            const float4 f1 = *(const float4*)&k[((size_t)(b * S + kt * BK + row)) * D + c8 * 8 + 4];
            bfv8 t;
            t[0] = (__bf16)f0.x; t[1] = (__bf16)f0.y; t[2] = (__bf16)f0.z; t[3] = (__bf16)f0.w;
            t[4] = (__bf16)f1.x; t[5] = (__bf16)f1.y; t[6] = (__bf16)f1.z; t[7] = (__bf16)f1.w;
            *(bfv8*)&ksm[row][c8 * 8] = t;
        }
        __syncthreads();

        f32x4 acc0 = {0.f, 0.f, 0.f, 0.f}, acc1 = {0.f, 0.f, 0.f, 0.f};
#pragma unroll
        for (int ks = 0; ks < 4; ++ks) {
            const bfv8 b0 = *(const bfv8*)&ksm[ch * 32 + lr][ks * 32 + lg * 8];
            const bfv8 b1 = *(const bfv8*)&ksm[ch * 32 + 16 + lr][ks * 32 + lg * 8];
            acc0 = mfma16(qa[ks], b0, acc0);
            acc1 = mfma16(qa[ks], b1, acc1);
        }
        const int j0 = kt * BK + ch * 32 + lr;
        const int j1 = j0 + 16;
        const bool vj0 = rep[(size_t)b * S + j0] > 0.5f;
        const bool vj1 = rep[(size_t)b * S + j1] > 0.5f;
#pragma unroll
        for (int r = 0; r < 4; ++r) {
            const int i = i_r[r];
            const float p0 = (bi[r] && vj0 && (j0 < i))
                ? __expf(acc0[r] * INV_SQRT_D - (float)(i - j0)) : 0.f;
            const float p1 = (bi[r] && vj1 && (j1 < i))
                ? __expf(acc1[r] * INV_SQRT_D - (float)(i - j1)) : 0.f;
            lsum[r] += p0 + p1;
        }
    }

#pragma unroll
    for (int r = 0; r < 4; ++r) {
        lsum[r] += __shfl_xor(lsum[r], 1);
        lsum[r] += __shfl_xor(lsum[r], 2);
        lsum[r] += __shfl_xor(lsum[r], 4);
        lsum[r] += __shfl_xor(lsum[r], 8);
    }
    if (lr == 0) {
#pragma unroll
        for (int r = 0; r < 4; ++r) redsum[rg][ch][lg * 4 + r] = lsum[r];
    }
    __syncthreads();
    if (tid < BQ) {
        const float s = redsum[tid >> 4][0][tid & 15] + redsum[tid >> 4][1][tid & 15];
        dinv_lds[tid] = 1.f / (s + ((s == 0.f) ? 1.f : 0.f) + 1e-20f);
    }
    __syncthreads();

    float dinv[4];
#pragma unroll
    for (int r = 0; r < 4; ++r) dinv[r] = dinv_lds[rg * 16 + lg * 4 + r];

    f32x4 oacc[4];
#pragma unroll
    for (int nf = 0; nf < 4; ++nf) oacc[nf] = (f32x4){0.f, 0.f, 0.f, 0.f};

    for (int kt = 0; kt < NT; ++kt) {
        __syncthreads();
        for (int c = tid; c < BK * 16; c += 256) {
            const int row = c >> 4, c8 = c & 15;
            const float4 f0 = *(const float4*)&k[((size_t)(b * S + kt * BK + row)) * D + c8 * 8];
            const float4 f1 = *(const float4*)&k[((size_t)(b * S + kt * BK + row)) * D + c8 * 8 + 4];
            bfv8 t;
            t[0] = (__bf16)f0.x; t[1] = (__bf16)f0.y; t[2] = (__bf16)f0.z; t[3] = (__bf16)f0.w;
            t[4] = (__bf16)f1.x; t[5] = (__bf16)f1.y; t[6] = (__bf16)f1.z; t[7] = (__bf16)f1.w;
            *(bfv8*)&ksm[row][c8 * 8] = t;
        }
        for (int u = tid; u < 1024; u += 256) {
            const int p  = u & 31;
            const int dq = u >> 5;
            const float4 va = *(const float4*)&v[((size_t)(b * S + kt * BK + 2 * p)) * D + dq * 4];
            const float4 vb = *(const float4*)&v[((size_t)(b * S + kt * BK + 2 * p + 1)) * D + dq * 4];
            *(unsigned int*)&vsT[dq * 4 + 0][2 * p] = pack2(va.x, vb.x);
            *(unsigned int*)&vsT[dq * 4 + 1][2 * p] = pack2(va.y, vb.y);
            *(unsigned int*)&vsT[dq * 4 + 2][2 * p] = pack2(va.z, vb.z);
            *(unsigned int*)&vsT[dq * 4 + 3][2 * p] = pack2(va.w, vb.w);
        }
        __syncthreads();

        f32x4 acc0 = {0.f, 0.f, 0.f, 0.f}, acc1 = {0.f, 0.f, 0.f, 0.f};
#pragma unroll
        for (int ks = 0; ks < 4; ++ks) {
            const bfv8 b0 = *(const bfv8*)&ksm[ch * 32 + lr][ks * 32 + lg * 8];
            const bfv8 b1 = *(const bfv8*)&ksm[ch * 32 + 16 + lr][ks * 32 + lg * 8];
            acc0 = mfma16(qa[ks], b0, acc0);
            acc1 = mfma16(qa[ks], b1, acc1);
        }
        const int j0 = kt * BK + ch * 32 + lr;
        const int j1 = j0 + 16;
        const bool vj0 = rep[(size_t)b * S + j0] > 0.5f;
        const bool vj1 = rep[(size_t)b * S + j1] > 0.5f;
#pragma unroll
        for (int r = 0; r < 4; ++r) {
            const int i = i_r[r];
            const float p0 = (bi[r] && vj0 && (j0 < i))
                ? __expf(acc0[r] * INV_SQRT_D - (float)(i - j0)) * dinv[r] : 0.f;
            const float p1 = (bi[r] && vj1 && (j1 < i))
                ? __expf(acc1[r] * INV_SQRT_D - (float)(i - j1)) * dinv[r] : 0.f;
            attn[((size_t)(b * S + i)) * S + j0] = p0;
            attn[((size_t)(b * S + i)) * S + j1] = p1;
            psl[rg * 16 + lg * 4 + r][ch * 32 + lr]      = (__bf16)p0;
            psl[rg * 16 + lg * 4 + r][ch * 32 + 16 + lr] = (__bf16)p1;
        }
        __syncthreads();

#pragma unroll
        for (int ks = 0; ks < 2; ++ks) {
            const bfv8 pa = *(const bfv8*)&psl[rg * 16 + lr][ks * 32 + lg * 8];
#pragma unroll
            for (int nf = 0; nf < 4; ++nf) {
                const bfv8 vf = *(const bfv8*)&vsT[ch * 64 + nf * 16 + lr][ks * 32 + lg * 8];
                oacc[nf] = mfma16(pa, vf, oacc[nf]);
            }
        }
    }

#pragma unroll
    for (int nf = 0; nf < 4; ++nf)
#pragma unroll
        for (int r = 0; r < 4; ++r)
            out[((size_t)(b * S + i_r[r])) * D + ch * 64 + nf * 16 + lr] = oacc[nf][r];

    const int zt = NKT - NT;
    const float4 z4 = make_float4(0.f, 0.f, 0.f, 0.f);
    for (int u = tid; u < zt * 512; u += 256) {
        const int t   = u >> 9;
        const int rem = u & 511;
        const int row = rem >> 4;
        const int c4  = rem & 15;
        *(float4*)&attn[((size_t)(b * S + i0 + row)) * S + (NT + t) * BK + c4 * 4] = z4;
    }
}

extern "C" void kernel_launch(void* const* d_in, const int* in_sizes, int n_in,
                              void* d_out, int out_size, void* d_ws, size_t ws_size,
                              hipStream_t stream)
{
    const float* q   = (const float*)d_in[0];
    const float* k   = (const float*)d_in[1];
    const float* v   = (const float*)d_in[2];
    const float* rep = (const float*)d_in[3];
    float* out  = (float*)d_out;
    float* attn = out + (size_t)NBATCH * S * D;

    const size_t kb_elems = (size_t)NBATCH * S * D;
    const size_t need     = kb_elems * 2 * 2;

    if (ws_size < need) {
        hipLaunchKernelGGL(attn_kernel_fb, dim3(NBATCH * NQT), dim3(256), 0, stream,
                           q, k, v, rep, out, attn);
        return;
    }

    __bf16* kb  = (__bf16*)d_ws;
    __bf16* vtb = kb + kb_elems;

    hipLaunchKernelGGL(prep_kernel, dim3(1280), dim3(256), 0, stream, k, v, kb, vtb);
    hipLaunchKernelGGL(attn_pc, dim3(NBATCH * NQT), dim3(512), 0, stream,
                       q, rep, kb, vtb, out, attn);
}